// Round 2
// baseline (1857.860 us; speedup 1.0000x reference)
//
#include <hip/hip_runtime.h>
#include <cstdint>

#define U64 unsigned long long

static constexpr int H = 38, W = 50, P = 1900;        // feature map
static constexpr int CIN = 2048, CMID = 256;
static constexpr int NA = 9, NBOX = 17100;            // 1900*9
static constexpr int HP = 40, WP = 52, QP = HP * WP;  // padded positions (2080)
static constexpr int KS = 7, CHUNK = 304;             // split-K over cin (304*7=2128>=2048, mult of 16)
static constexpr int NW = 268;                        // u64 words covering NBOX bits
static constexpr int MSTRIDE = 272;                   // padded mask row stride (u64)
static constexpr float NMS_T = 0.5f;
static constexpr int QTILE = 128;
static constexpr int QTILES = (QP + QTILE - 1) / QTILE; // 17

// ---------------- ws layout (bytes) ----------------
static constexpr size_t SZ_INT  = (size_t)QP * CIN * 4;       // 17,039,360
static constexpr size_t SZ_WT   = (size_t)9 * CIN * CMID * 4; // 18,874,368
static constexpr size_t SZ_PART = (size_t)KS * P * CMID * 4;  // 13,619,200
static constexpr size_t OFF_INT  = 0;
static constexpr size_t OFF_WT   = OFF_INT + SZ_INT;
static constexpr size_t OFF_PART = OFF_WT + SZ_WT;
static constexpr size_t REGA     = OFF_PART + SZ_PART;        // 49,532,928
static constexpr size_t OFF_MASK = 0;                          // overlays region A (dead by then)
static constexpr size_t OFF_MID  = REGA;                       // [P][CMID] f32
static constexpr size_t OFF_FG   = OFF_MID + 1945600;
static constexpr size_t OFF_BOX  = OFF_FG + 68608;
static constexpr size_t OFF_SBOX = OFF_BOX + 273664;
static constexpr size_t OFF_SAREA= OFF_SBOX + 273664;
static constexpr size_t WS_NEED  = OFF_SAREA + 68608;          // 52,163,072

// ---------------- kernels ----------------

__global__ __launch_bounds__(256) void k_sentinel(float* out, int n) {
    int i = blockIdx.x * 256 + threadIdx.x;
    if (i < n) out[i] = 1.2345678e8f;
}

// feature_map [CIN][H][W] -> in_t [QP][CIN] (padded, zero border; memset first)
__global__ __launch_bounds__(256) void k_in_t(const float* __restrict__ fm, float* __restrict__ in_t) {
    __shared__ float tl[64][53];
    int h = blockIdx.x, cb = blockIdx.y, t = threadIdx.x;
    for (int idx = t; idx < 64 * 50; idx += 256) {
        int ci = idx / 50, w = idx % 50;
        tl[ci][w] = fm[(size_t)(cb * 64 + ci) * (H * W) + h * W + w];
    }
    __syncthreads();
    for (int idx = t; idx < 50 * 64; idx += 256) {
        int w = idx / 64, ci = idx % 64;
        in_t[(size_t)((h + 1) * WP + (w + 1)) * CIN + cb * 64 + ci] = tl[ci][w];
    }
}

// conv_w [CMID][CIN][3][3] -> w_t [9][CIN][CMID]
__global__ __launch_bounds__(256) void k_w_t(const float* __restrict__ cw, float* __restrict__ wt) {
    __shared__ float tl[64][65];
    int x0 = blockIdx.x * 64, c0 = blockIdx.y * 64, t = threadIdx.x;
    for (int rep = 0; rep < 16; ++rep) {
        int lin = rep * 256 + t;
        int row = lin / 64, col = lin % 64; // row: cout offset, col: x offset
        tl[row][col] = cw[(size_t)(c0 + row) * (CIN * 9) + x0 + col];
    }
    __syncthreads();
    for (int rep = 0; rep < 16; ++rep) {
        int lin = rep * 256 + t;
        int xr = lin / 64, cr = lin % 64;
        int x = x0 + xr;
        int k = x % 9, cin = x / 9;
        wt[((size_t)k * CIN + cin) * CMID + c0 + cr] = tl[cr][xr];
    }
}

// 3x3 conv, split-K. grid (17 q-tiles of 128, 8 cout-groups of 32, KS)
// thread: 1 q x 16 cout. LDS: s_in [16][241] (pad->conflict-free), s_w [16][9][32].
__global__ __launch_bounds__(256) void k_conv(const float* __restrict__ in_t,
                                              const float* __restrict__ wt,
                                              float* __restrict__ partial) {
    __shared__ float s_in[16 * 241];
    __shared__ float s_w[16 * 9 * 32];
    int t = threadIdx.x;
    int tq = t & 127;           // q within tile
    int tc16 = (t >> 7) * 16;   // cout sub-block (wave-uniform)
    int q0 = blockIdx.x * QTILE;
    int cout0 = blockIdx.y * 32;
    int cin0 = blockIdx.z * CHUNK;
    int cin1 = min(CIN, cin0 + CHUNK);
    float acc[16];
#pragma unroll
    for (int c = 0; c < 16; ++c) acc[c] = 0.f;

    for (int c0 = cin0; c0 < cin1; c0 += 16) {
        // stage input: x in [0,240), 4 ci per float4. conflict-free writes (stride-1 x).
        for (int idx = t; idx < 960; idx += 256) {
            int ci4 = idx & 3, x = idx >> 2;
            int q = q0 - 53 + x;
            float4 v = make_float4(0.f, 0.f, 0.f, 0.f);
            if (q >= 0 && q < QP)
                v = *reinterpret_cast<const float4*>(in_t + (size_t)q * CIN + c0 + ci4 * 4);
            int r = (ci4 * 4) * 241 + x;
            s_in[r] = v.x; s_in[r + 241] = v.y; s_in[r + 482] = v.z; s_in[r + 723] = v.w;
        }
        // stage weights: [ci][k][32], float4 (8 lanes * 16B = 128B global segments)
        for (int idx = t; idx < 1152; idx += 256) {
            int c4 = idx & 7, r = idx >> 3;
            int ci = r / 9, k = r - ci * 9;
            float4 v = *reinterpret_cast<const float4*>(
                wt + ((size_t)k * CIN + c0 + ci) * CMID + cout0 + c4 * 4);
            reinterpret_cast<float4*>(s_w)[((ci * 9 + k) * 32 + c4 * 4) >> 2] = v;
        }
        __syncthreads();
#pragma unroll 1
        for (int ci = 0; ci < 16; ++ci) {
            const float* si = s_in + ci * 241 + tq + 53;
            const float* swb = s_w + ci * 9 * 32 + tc16;
#pragma unroll
            for (int k = 0; k < 9; ++k) {
                const int DQ[9] = {-53, -52, -51, -1, 0, 1, 51, 52, 53};
                float iv = si[DQ[k]];
                const float4* wp = reinterpret_cast<const float4*>(swb + k * 32);
                float4 w0 = wp[0], w1 = wp[1], w2 = wp[2], w3 = wp[3];
                acc[0]  += iv * w0.x; acc[1]  += iv * w0.y; acc[2]  += iv * w0.z; acc[3]  += iv * w0.w;
                acc[4]  += iv * w1.x; acc[5]  += iv * w1.y; acc[6]  += iv * w1.z; acc[7]  += iv * w1.w;
                acc[8]  += iv * w2.x; acc[9]  += iv * w2.y; acc[10] += iv * w2.z; acc[11] += iv * w2.w;
                acc[12] += iv * w3.x; acc[13] += iv * w3.y; acc[14] += iv * w3.z; acc[15] += iv * w3.w;
            }
        }
        __syncthreads();
    }
    int q = q0 + tq;
    if (q < QP) {
        int hp = q / WP, wp_ = q - hp * WP;
        if (hp >= 1 && hp <= H && wp_ >= 1 && wp_ <= W) {
            int p = (hp - 1) * W + (wp_ - 1);
            float* dst = partial + (size_t)blockIdx.z * P * CMID + (size_t)p * CMID + cout0 + tc16;
            float4* d4 = reinterpret_cast<float4*>(dst);
            d4[0] = make_float4(acc[0], acc[1], acc[2], acc[3]);
            d4[1] = make_float4(acc[4], acc[5], acc[6], acc[7]);
            d4[2] = make_float4(acc[8], acc[9], acc[10], acc[11]);
            d4[3] = make_float4(acc[12], acc[13], acc[14], acc[15]);
        }
    }
}

// sum partials + bias + relu -> mid [P][CMID]
__global__ __launch_bounds__(256) void k_reduce(const float* __restrict__ partial,
                                                const float* __restrict__ bias,
                                                float* __restrict__ mid) {
    int p = blockIdx.x, c = threadIdx.x;
    float s = bias[c];
    for (int ks = 0; ks < KS; ++ks) s += partial[(size_t)ks * P * CMID + (size_t)p * CMID + c];
    mid[(size_t)p * CMID + c] = fmaxf(s, 0.f);
}

// 1x1 heads + softmax + anchors + loc2bbox + clip. 4 positions per block.
__global__ __launch_bounds__(256) void k_heads(const float* __restrict__ mid,
                                               const float* __restrict__ score_w,
                                               const float* __restrict__ score_b,
                                               const float* __restrict__ loc_w,
                                               const float* __restrict__ loc_b,
                                               float* __restrict__ score_out,
                                               float* __restrict__ loc_out,
                                               float* __restrict__ anch_out,
                                               float* __restrict__ fg,
                                               float* __restrict__ boxes) {
    __shared__ float wl[256][56];
    __shared__ float bias[56];
    __shared__ float dots[4][64];
    int t = threadIdx.x;
    for (int idx = t; idx < 18 * 256; idx += 256) {
        int c = idx >> 8, i = idx & 255;
        wl[i][c] = score_w[idx];
    }
    for (int idx = t; idx < 36 * 256; idx += 256) {
        int c = idx >> 8, i = idx & 255;
        wl[i][18 + c] = loc_w[idx];
    }
    if (t < 18) bias[t] = score_b[t];
    else if (t < 54) bias[t] = loc_b[t - 18];
    __syncthreads();

    int pl = t >> 6, c = t & 63;
    int p = blockIdx.x * 4 + pl;
    if (c < 54) {
        float d = bias[c];
        const float4* mp = reinterpret_cast<const float4*>(mid + (size_t)p * CMID);
        for (int i4 = 0; i4 < 64; ++i4) {
            float4 m4 = mp[i4];
            int i = i4 * 4;
            d += m4.x * wl[i][c] + m4.y * wl[i + 1][c] + m4.z * wl[i + 2][c] + m4.w * wl[i + 3][c];
        }
        dots[pl][c] = d;
    }
    __syncthreads();

    if (c < NA) {
        int a = c;
        int idx = p * NA + a;
        // softmax pair
        float l0 = dots[pl][2 * a], l1 = dots[pl][2 * a + 1];
        float mx = fmaxf(l0, l1);
        float e0 = expf(l0 - mx), e1 = expf(l1 - mx);
        float den = e0 + e1;
        float s0 = e0 / den, s1 = e1 / den;
        score_out[(size_t)idx * 2 + 0] = s0;
        score_out[(size_t)idx * 2 + 1] = s1;
        fg[idx] = s1;
        // loc
        float dx = dots[pl][18 + 4 * a + 0];
        float dy = dots[pl][18 + 4 * a + 1];
        float dw = dots[pl][18 + 4 * a + 2];
        float dh = dots[pl][18 + 4 * a + 3];
        loc_out[(size_t)idx * 4 + 0] = dx;
        loc_out[(size_t)idx * 4 + 1] = dy;
        loc_out[(size_t)idx * 4 + 2] = dw;
        loc_out[(size_t)idx * 4 + 3] = dh;
        // anchor (f64 base, f32 add -- matches numpy)
        int hh = p / W, ww = p % W;
        const double scales[3] = {8.0, 16.0, 32.0};
        const double ratios[3] = {0.5, 1.0, 2.0};
        double s = scales[a / 3], r = ratios[a % 3];
        double wb = 16.0 * s * sqrt(r);
        double hb = wb / r;
        double xmin = 8.0 - wb / 2.0, ymin = 8.0 - hb / 2.0;
        float b0 = (float)xmin, b1 = (float)ymin;
        float b2 = (float)(xmin + wb), b3 = (float)(ymin + hb);
        float gx = (float)(ww * 16), gy = (float)(hh * 16);
        float a0 = gx + b0, a1 = gy + b1, a2 = gx + b2, a3 = gy + b3;
        anch_out[(size_t)idx * 4 + 0] = a0;
        anch_out[(size_t)idx * 4 + 1] = a1;
        anch_out[(size_t)idx * 4 + 2] = a2;
        anch_out[(size_t)idx * 4 + 3] = a3;
        // loc2bbox + clip
        float aw = a2 - a0, ah = a3 - a1;
        float cx = a0 + 0.5f * aw, cy = a1 + 0.5f * ah;
        float ncx = dx * aw + cx, ncy = dy * ah + cy;
        float nw = expf(dw) * aw, nh = expf(dh) * ah;
        float x1 = ncx - 0.5f * nw, y1 = ncy - 0.5f * nh;
        float x2 = ncx + 0.5f * nw, y2 = ncy + 0.5f * nh;
        x1 = fminf(fmaxf(x1, 0.f), (float)(W * 16));
        x2 = fminf(fmaxf(x2, 0.f), (float)(W * 16));
        y1 = fminf(fmaxf(y1, 0.f), (float)(H * 16));
        y2 = fminf(fmaxf(y2, 0.f), (float)(H * 16));
        float4* bp = reinterpret_cast<float4*>(boxes);
        bp[idx] = make_float4(x1, y1, x2, y2);
    }
}

// stable descending rank; scatter boxes to sorted order
__global__ __launch_bounds__(256) void k_rank(const float* __restrict__ fg,
                                              const float* __restrict__ boxes,
                                              float* __restrict__ sboxes,
                                              float* __restrict__ sarea) {
    __shared__ float4 tile[256];
    int t = threadIdx.x;
    int i = blockIdx.x * 256 + t;
    float my = (i < NBOX) ? fg[i] : 0.f;
    int cnt = 0;
    for (int jt = 0; jt < 17; ++jt) {
        int j = jt * 1024 + t * 4;
        float4 v = make_float4(-3.4e38f, -3.4e38f, -3.4e38f, -3.4e38f);
        if (j < NBOX) v = *reinterpret_cast<const float4*>(fg + j);  // NBOX % 4 == 0
        __syncthreads();
        tile[t] = v;
        __syncthreads();
        if (i < NBOX) {
            int jb0 = jt * 1024;
            for (int u = 0; u < 256; ++u) {
                float4 s = tile[u];
                int jb = jb0 + u * 4;
                cnt += (s.x > my) || (s.x == my && jb < i);
                cnt += (s.y > my) || (s.y == my && jb + 1 < i);
                cnt += (s.z > my) || (s.z == my && jb + 2 < i);
                cnt += (s.w > my) || (s.w == my && jb + 3 < i);
            }
        }
    }
    if (i < NBOX) {
        float4 b = reinterpret_cast<const float4*>(boxes)[i];
        reinterpret_cast<float4*>(sboxes)[cnt] = b;
        sarea[cnt] = (b.z - b.x) * (b.w - b.y);
    }
}

// NMS pair bitmask: mask[i][w] bit jb = (IoU(i, w*64+jb) > T && j > i)
__global__ __launch_bounds__(256) void k_maskfill(const float* __restrict__ sboxes,
                                                  const float* __restrict__ sarea,
                                                  U64* __restrict__ mask) {
    int w = blockIdx.y;
    int i0 = blockIdx.x * 256;
    if (w < (i0 >> 6)) return;
    __shared__ float4 sb[64];
    __shared__ float sa[64];
    int t = threadIdx.x;
    if (t < 64) {
        int j = w * 64 + t;
        if (j < NBOX) {
            sb[t] = reinterpret_cast<const float4*>(sboxes)[j];
            sa[t] = sarea[j];
        } else {
            sb[t] = make_float4(0.f, 0.f, 0.f, 0.f);
            sa[t] = 0.f;
        }
    }
    __syncthreads();
    int i = i0 + t;
    if (i >= NBOX || w < (i >> 6)) return;
    float4 bi = reinterpret_cast<const float4*>(sboxes)[i];
    float ai = sarea[i];
    U64 word = 0;
#pragma unroll 4
    for (int jb = 0; jb < 64; ++jb) {
        int j = w * 64 + jb;
        float4 bj = sb[jb];
        float xx1 = fmaxf(bi.x, bj.x), yy1 = fmaxf(bi.y, bj.y);
        float xx2 = fminf(bi.z, bj.z), yy2 = fminf(bi.w, bj.w);
        float inter = fmaxf(xx2 - xx1, 0.f) * fmaxf(yy2 - yy1, 0.f);
        float iou = inter / (ai + sa[jb] - inter);
        word |= ((U64)((iou > NMS_T) && (j > i))) << jb;
    }
    mask[(size_t)i * MSTRIDE + w] = word;
}

// exact greedy sweep: double-buffered diag prefetch + shfl resolve + klist cross-OR
__global__ __launch_bounds__(256) void k_sweep(const U64* __restrict__ mask,
                                               const float* __restrict__ sboxes,
                                               float* __restrict__ rois_out,
                                               float* __restrict__ keep_out) {
    __shared__ U64 rem[NW];
    __shared__ U64 diag[2][64];
    __shared__ int klist[64];
    __shared__ unsigned base_s;
    int t = threadIdx.x;
    for (int u = t; u < NW; u += 256) rem[u] = 0;
    if (t == 0) base_s = 0;
    if (t < 64) diag[0][t] = mask[(size_t)t * MSTRIDE + 0];
    __syncthreads();

    for (int g = 0; g < NW; ++g) {
        int nv = min(64, NBOX - g * 64);
        U64 vmask = (nv == 64) ? ~0ull : ((1ull << nv) - 1);

        // (A) prefetch next diagonal block (latency hidden under resolve+OR)
        U64 nxtval = 0;
        if (t < 64 && g + 1 < NW) {
            int row = (g + 1) * 64 + t;
            if (row < NBOX) nxtval = mask[(size_t)row * MSTRIDE + (g + 1)];
        }

        // (B) resolve via wave shuffle (each wave redundantly computes identical m)
        U64 myw = diag[g & 1][t & 63];
        U64 m = rem[g];
        for (int ii = 0; ii < 64; ++ii) {
            U64 wi = __shfl(myw, ii, 64);
            if (!((m >> ii) & 1ull)) m |= wi;
        }
        U64 kept = ~m & vmask;
        int nk = __popcll(kept);
        unsigned base = base_s;

        // (C) outputs + klist
        if (t < 64) {
            bool mk = (t < nv) && ((kept >> t) & 1ull);
            if (mk) {
                unsigned pre = (t == 0) ? 0u : (unsigned)__popcll(kept & ((1ull << t) - 1));
                unsigned dst = base + pre;
                float4 bb = reinterpret_cast<const float4*>(sboxes)[g * 64 + t];
                reinterpret_cast<float4*>(rois_out)[dst] = bb;
                keep_out[dst] = 1.0f;
                klist[pre] = t;
            }
        }
        __syncthreads();   // klist visible; everyone has read base_s

        if (t == 0) base_s = base + (unsigned)nk;

        // (D) cross-group OR using klist (independent, pipelined loads)
        const U64* grow = mask + (size_t)g * 64 * MSTRIDE;
        for (int w = g + 1 + t; w < NW; w += 256) {
            U64 acc = rem[w];
            int b = 0;
            for (; b + 3 < nk; b += 4) {
                int r0 = klist[b], r1 = klist[b + 1], r2 = klist[b + 2], r3 = klist[b + 3];
                U64 v0 = grow[(size_t)r0 * MSTRIDE + w];
                U64 v1 = grow[(size_t)r1 * MSTRIDE + w];
                U64 v2 = grow[(size_t)r2 * MSTRIDE + w];
                U64 v3 = grow[(size_t)r3 * MSTRIDE + w];
                acc |= v0 | v1 | v2 | v3;
            }
            for (; b < nk; ++b)
                acc |= grow[(size_t)klist[b] * MSTRIDE + w];
            rem[w] = acc;
        }
        if (t < 64) diag[(g + 1) & 1][t] = nxtval;
        __syncthreads();
    }
}

// ---------------- launch ----------------
extern "C" void kernel_launch(void* const* d_in, const int* in_sizes, int n_in,
                              void* d_out, int out_size, void* d_ws, size_t ws_size,
                              hipStream_t stream) {
    const float* fm      = (const float*)d_in[0];
    const float* conv_w  = (const float*)d_in[2];
    const float* conv_b  = (const float*)d_in[3];
    const float* score_w = (const float*)d_in[4];
    const float* score_b = (const float*)d_in[5];
    const float* loc_w   = (const float*)d_in[6];
    const float* loc_b   = (const float*)d_in[7];

    float* out = (float*)d_out;
    float* rois_out  = out;
    float* keep_out  = out + NBOX * 4;
    float* anch_out  = out + NBOX * 5;
    float* loc_out   = out + NBOX * 9;
    float* score_out = out + NBOX * 13;

    if (ws_size < WS_NEED) {
        k_sentinel<<<(out_size + 255) / 256, 256, 0, stream>>>(out, out_size);
        return;
    }

    char* ws = (char*)d_ws;
    float* in_t    = (float*)(ws + OFF_INT);
    float* wt      = (float*)(ws + OFF_WT);
    float* partial = (float*)(ws + OFF_PART);
    U64*   mask    = (U64*)(ws + OFF_MASK);
    float* mid     = (float*)(ws + OFF_MID);
    float* fg      = (float*)(ws + OFF_FG);
    float* boxes   = (float*)(ws + OFF_BOX);
    float* sboxes  = (float*)(ws + OFF_SBOX);
    float* sarea   = (float*)(ws + OFF_SAREA);

    hipMemsetAsync(in_t, 0, SZ_INT, stream);
    k_in_t<<<dim3(H, CIN / 64), 256, 0, stream>>>(fm, in_t);
    k_w_t<<<dim3(CIN * 9 / 64, CMID / 64), 256, 0, stream>>>(conv_w, wt);
    k_conv<<<dim3(QTILES, 8, KS), 256, 0, stream>>>(in_t, wt, partial);
    k_reduce<<<P, 256, 0, stream>>>(partial, conv_b, mid);
    k_heads<<<P / 4, 256, 0, stream>>>(mid, score_w, score_b, loc_w, loc_b,
                                       score_out, loc_out, anch_out, fg, boxes);
    k_rank<<<(NBOX + 255) / 256, 256, 0, stream>>>(fg, boxes, sboxes, sarea);
    hipMemsetAsync(rois_out, 0, (size_t)NBOX * 5 * 4, stream);  // rois_out + keep
    k_maskfill<<<dim3((NBOX + 255) / 256, NW), 256, 0, stream>>>(sboxes, sarea, mask);
    k_sweep<<<1, 256, 0, stream>>>(mask, sboxes, rois_out, keep_out);
}

// Round 3
// 1399.801 us; speedup vs baseline: 1.3272x; 1.3272x over previous
//
#include <hip/hip_runtime.h>
#include <cstdint>

#define U64 unsigned long long

static constexpr int H = 38, W = 50, P = 1900;        // feature map
static constexpr int CIN = 2048, CMID = 256;
static constexpr int NA = 9, NBOX = 17100;            // 1900*9
static constexpr int HP = 40, WP = 52, QP = HP * WP;  // padded positions (2080)
static constexpr int KS = 7, CHUNK = 304;             // split-K over cin (304*7=2128>=2048, mult of 16)
static constexpr int NW = 268;                        // u64 words covering NBOX bits
static constexpr int PITCH = 17152;                   // maskT row pitch (words), mult of 64
static constexpr float NMS_T = 0.5f;
static constexpr int QTILE = 128;
static constexpr int QTILES = (QP + QTILE - 1) / QTILE; // 17

// ---------------- ws layout (bytes) ----------------
static constexpr size_t SZ_INT  = (size_t)QP * CIN * 4;       // 17,039,360
static constexpr size_t SZ_WT   = (size_t)9 * CIN * CMID * 4; // 18,874,368
static constexpr size_t SZ_PART = (size_t)KS * P * CMID * 4;  // 13,619,200
static constexpr size_t OFF_INT  = 0;
static constexpr size_t OFF_WT   = OFF_INT + SZ_INT;
static constexpr size_t OFF_PART = OFF_WT + SZ_WT;
static constexpr size_t REGA     = OFF_PART + SZ_PART;        // 49,532,928
static constexpr size_t OFF_MASK = 0;                          // maskT [NW][PITCH] u64, 36.8 MB, overlays region A
static constexpr size_t OFF_MID  = REGA;                       // [P][CMID] f32
static constexpr size_t OFF_FG   = OFF_MID + 1945600;
static constexpr size_t OFF_BOX  = OFF_FG + 68608;
static constexpr size_t OFF_SBOX = OFF_BOX + 273664;
static constexpr size_t OFF_SAREA= OFF_SBOX + 273664;
static constexpr size_t WS_NEED  = OFF_SAREA + 68608;          // 52,163,072

__device__ __forceinline__ U64 rdlane64(U64 v, int l) {
    unsigned lo = (unsigned)__builtin_amdgcn_readlane((int)(unsigned)(v & 0xffffffffull), l);
    unsigned hi = (unsigned)__builtin_amdgcn_readlane((int)(unsigned)(v >> 32), l);
    return ((U64)hi << 32) | (U64)lo;
}

// ---------------- kernels ----------------

__global__ __launch_bounds__(256) void k_sentinel(float* out, int n) {
    int i = blockIdx.x * 256 + threadIdx.x;
    if (i < n) out[i] = 1.2345678e8f;
}

// feature_map [CIN][H][W] -> in_t [QP][CIN] (padded, zero border; memset first)
__global__ __launch_bounds__(256) void k_in_t(const float* __restrict__ fm, float* __restrict__ in_t) {
    __shared__ float tl[64][53];
    int h = blockIdx.x, cb = blockIdx.y, t = threadIdx.x;
    for (int idx = t; idx < 64 * 50; idx += 256) {
        int ci = idx / 50, w = idx % 50;
        tl[ci][w] = fm[(size_t)(cb * 64 + ci) * (H * W) + h * W + w];
    }
    __syncthreads();
    for (int idx = t; idx < 50 * 64; idx += 256) {
        int w = idx / 64, ci = idx % 64;
        in_t[(size_t)((h + 1) * WP + (w + 1)) * CIN + cb * 64 + ci] = tl[ci][w];
    }
}

// conv_w [CMID][CIN][3][3] -> w_t [9][CIN][CMID]
__global__ __launch_bounds__(256) void k_w_t(const float* __restrict__ cw, float* __restrict__ wt) {
    __shared__ float tl[64][65];
    int x0 = blockIdx.x * 64, c0 = blockIdx.y * 64, t = threadIdx.x;
    for (int rep = 0; rep < 16; ++rep) {
        int lin = rep * 256 + t;
        int row = lin / 64, col = lin % 64; // row: cout offset, col: x offset
        tl[row][col] = cw[(size_t)(c0 + row) * (CIN * 9) + x0 + col];
    }
    __syncthreads();
    for (int rep = 0; rep < 16; ++rep) {
        int lin = rep * 256 + t;
        int xr = lin / 64, cr = lin % 64;
        int x = x0 + xr;
        int k = x % 9, cin = x / 9;
        wt[((size_t)k * CIN + cin) * CMID + c0 + cr] = tl[cr][xr];
    }
}

// 3x3 conv, split-K. grid (17 q-tiles of 128, 8 cout-groups of 32, KS)
__global__ __launch_bounds__(256) void k_conv(const float* __restrict__ in_t,
                                              const float* __restrict__ wt,
                                              float* __restrict__ partial) {
    __shared__ float s_in[16 * 241];
    __shared__ float s_w[16 * 9 * 32];
    int t = threadIdx.x;
    int tq = t & 127;           // q within tile
    int tc16 = (t >> 7) * 16;   // cout sub-block (wave-uniform)
    int q0 = blockIdx.x * QTILE;
    int cout0 = blockIdx.y * 32;
    int cin0 = blockIdx.z * CHUNK;
    int cin1 = min(CIN, cin0 + CHUNK);
    float acc[16];
#pragma unroll
    for (int c = 0; c < 16; ++c) acc[c] = 0.f;

    for (int c0 = cin0; c0 < cin1; c0 += 16) {
        for (int idx = t; idx < 960; idx += 256) {
            int ci4 = idx & 3, x = idx >> 2;
            int q = q0 - 53 + x;
            float4 v = make_float4(0.f, 0.f, 0.f, 0.f);
            if (q >= 0 && q < QP)
                v = *reinterpret_cast<const float4*>(in_t + (size_t)q * CIN + c0 + ci4 * 4);
            int r = (ci4 * 4) * 241 + x;
            s_in[r] = v.x; s_in[r + 241] = v.y; s_in[r + 482] = v.z; s_in[r + 723] = v.w;
        }
        for (int idx = t; idx < 1152; idx += 256) {
            int c4 = idx & 7, r = idx >> 3;
            int ci = r / 9, k = r - ci * 9;
            float4 v = *reinterpret_cast<const float4*>(
                wt + ((size_t)k * CIN + c0 + ci) * CMID + cout0 + c4 * 4);
            reinterpret_cast<float4*>(s_w)[((ci * 9 + k) * 32 + c4 * 4) >> 2] = v;
        }
        __syncthreads();
#pragma unroll 1
        for (int ci = 0; ci < 16; ++ci) {
            const float* si = s_in + ci * 241 + tq + 53;
            const float* swb = s_w + ci * 9 * 32 + tc16;
#pragma unroll
            for (int k = 0; k < 9; ++k) {
                const int DQ[9] = {-53, -52, -51, -1, 0, 1, 51, 52, 53};
                float iv = si[DQ[k]];
                const float4* wp = reinterpret_cast<const float4*>(swb + k * 32);
                float4 w0 = wp[0], w1 = wp[1], w2 = wp[2], w3 = wp[3];
                acc[0]  += iv * w0.x; acc[1]  += iv * w0.y; acc[2]  += iv * w0.z; acc[3]  += iv * w0.w;
                acc[4]  += iv * w1.x; acc[5]  += iv * w1.y; acc[6]  += iv * w1.z; acc[7]  += iv * w1.w;
                acc[8]  += iv * w2.x; acc[9]  += iv * w2.y; acc[10] += iv * w2.z; acc[11] += iv * w2.w;
                acc[12] += iv * w3.x; acc[13] += iv * w3.y; acc[14] += iv * w3.z; acc[15] += iv * w3.w;
            }
        }
        __syncthreads();
    }
    int q = q0 + tq;
    if (q < QP) {
        int hp = q / WP, wp_ = q - hp * WP;
        if (hp >= 1 && hp <= H && wp_ >= 1 && wp_ <= W) {
            int p = (hp - 1) * W + (wp_ - 1);
            float* dst = partial + (size_t)blockIdx.z * P * CMID + (size_t)p * CMID + cout0 + tc16;
            float4* d4 = reinterpret_cast<float4*>(dst);
            d4[0] = make_float4(acc[0], acc[1], acc[2], acc[3]);
            d4[1] = make_float4(acc[4], acc[5], acc[6], acc[7]);
            d4[2] = make_float4(acc[8], acc[9], acc[10], acc[11]);
            d4[3] = make_float4(acc[12], acc[13], acc[14], acc[15]);
        }
    }
}

// sum partials + bias + relu -> mid [P][CMID]
__global__ __launch_bounds__(256) void k_reduce(const float* __restrict__ partial,
                                                const float* __restrict__ bias,
                                                float* __restrict__ mid) {
    int p = blockIdx.x, c = threadIdx.x;
    float s = bias[c];
    for (int ks = 0; ks < KS; ++ks) s += partial[(size_t)ks * P * CMID + (size_t)p * CMID + c];
    mid[(size_t)p * CMID + c] = fmaxf(s, 0.f);
}

// 1x1 heads + softmax + anchors + loc2bbox + clip. 4 positions per block.
__global__ __launch_bounds__(256) void k_heads(const float* __restrict__ mid,
                                               const float* __restrict__ score_w,
                                               const float* __restrict__ score_b,
                                               const float* __restrict__ loc_w,
                                               const float* __restrict__ loc_b,
                                               float* __restrict__ score_out,
                                               float* __restrict__ loc_out,
                                               float* __restrict__ anch_out,
                                               float* __restrict__ fg,
                                               float* __restrict__ boxes) {
    __shared__ float wl[256][56];
    __shared__ float bias[56];
    __shared__ float dots[4][64];
    int t = threadIdx.x;
    for (int idx = t; idx < 18 * 256; idx += 256) {
        int c = idx >> 8, i = idx & 255;
        wl[i][c] = score_w[idx];
    }
    for (int idx = t; idx < 36 * 256; idx += 256) {
        int c = idx >> 8, i = idx & 255;
        wl[i][18 + c] = loc_w[idx];
    }
    if (t < 18) bias[t] = score_b[t];
    else if (t < 54) bias[t] = loc_b[t - 18];
    __syncthreads();

    int pl = t >> 6, c = t & 63;
    int p = blockIdx.x * 4 + pl;
    if (c < 54) {
        float d = bias[c];
        const float4* mp = reinterpret_cast<const float4*>(mid + (size_t)p * CMID);
        for (int i4 = 0; i4 < 64; ++i4) {
            float4 m4 = mp[i4];
            int i = i4 * 4;
            d += m4.x * wl[i][c] + m4.y * wl[i + 1][c] + m4.z * wl[i + 2][c] + m4.w * wl[i + 3][c];
        }
        dots[pl][c] = d;
    }
    __syncthreads();

    if (c < NA) {
        int a = c;
        int idx = p * NA + a;
        float l0 = dots[pl][2 * a], l1 = dots[pl][2 * a + 1];
        float mx = fmaxf(l0, l1);
        float e0 = expf(l0 - mx), e1 = expf(l1 - mx);
        float den = e0 + e1;
        float s0 = e0 / den, s1 = e1 / den;
        score_out[(size_t)idx * 2 + 0] = s0;
        score_out[(size_t)idx * 2 + 1] = s1;
        fg[idx] = s1;
        float dx = dots[pl][18 + 4 * a + 0];
        float dy = dots[pl][18 + 4 * a + 1];
        float dw = dots[pl][18 + 4 * a + 2];
        float dh = dots[pl][18 + 4 * a + 3];
        loc_out[(size_t)idx * 4 + 0] = dx;
        loc_out[(size_t)idx * 4 + 1] = dy;
        loc_out[(size_t)idx * 4 + 2] = dw;
        loc_out[(size_t)idx * 4 + 3] = dh;
        int hh = p / W, ww = p % W;
        const double scales[3] = {8.0, 16.0, 32.0};
        const double ratios[3] = {0.5, 1.0, 2.0};
        double s = scales[a / 3], r = ratios[a % 3];
        double wb = 16.0 * s * sqrt(r);
        double hb = wb / r;
        double xmin = 8.0 - wb / 2.0, ymin = 8.0 - hb / 2.0;
        float b0 = (float)xmin, b1 = (float)ymin;
        float b2 = (float)(xmin + wb), b3 = (float)(ymin + hb);
        float gx = (float)(ww * 16), gy = (float)(hh * 16);
        float a0 = gx + b0, a1 = gy + b1, a2 = gx + b2, a3 = gy + b3;
        anch_out[(size_t)idx * 4 + 0] = a0;
        anch_out[(size_t)idx * 4 + 1] = a1;
        anch_out[(size_t)idx * 4 + 2] = a2;
        anch_out[(size_t)idx * 4 + 3] = a3;
        float aw = a2 - a0, ah = a3 - a1;
        float cx = a0 + 0.5f * aw, cy = a1 + 0.5f * ah;
        float ncx = dx * aw + cx, ncy = dy * ah + cy;
        float nw = expf(dw) * aw, nh = expf(dh) * ah;
        float x1 = ncx - 0.5f * nw, y1 = ncy - 0.5f * nh;
        float x2 = ncx + 0.5f * nw, y2 = ncy + 0.5f * nh;
        x1 = fminf(fmaxf(x1, 0.f), (float)(W * 16));
        x2 = fminf(fmaxf(x2, 0.f), (float)(W * 16));
        y1 = fminf(fmaxf(y1, 0.f), (float)(H * 16));
        y2 = fminf(fmaxf(y2, 0.f), (float)(H * 16));
        float4* bp = reinterpret_cast<float4*>(boxes);
        bp[idx] = make_float4(x1, y1, x2, y2);
    }
}

// stable descending rank; scatter boxes to sorted order
__global__ __launch_bounds__(256) void k_rank(const float* __restrict__ fg,
                                              const float* __restrict__ boxes,
                                              float* __restrict__ sboxes,
                                              float* __restrict__ sarea) {
    __shared__ float4 tile[256];
    int t = threadIdx.x;
    int i = blockIdx.x * 256 + t;
    float my = (i < NBOX) ? fg[i] : 0.f;
    int cnt = 0;
    for (int jt = 0; jt < 17; ++jt) {
        int j = jt * 1024 + t * 4;
        float4 v = make_float4(-3.4e38f, -3.4e38f, -3.4e38f, -3.4e38f);
        if (j < NBOX) v = *reinterpret_cast<const float4*>(fg + j);  // NBOX % 4 == 0
        __syncthreads();
        tile[t] = v;
        __syncthreads();
        if (i < NBOX) {
            int jb0 = jt * 1024;
            for (int u = 0; u < 256; ++u) {
                float4 s = tile[u];
                int jb = jb0 + u * 4;
                cnt += (s.x > my) || (s.x == my && jb < i);
                cnt += (s.y > my) || (s.y == my && jb + 1 < i);
                cnt += (s.z > my) || (s.z == my && jb + 2 < i);
                cnt += (s.w > my) || (s.w == my && jb + 3 < i);
            }
        }
    }
    if (i < NBOX) {
        float4 b = reinterpret_cast<const float4*>(boxes)[i];
        reinterpret_cast<float4*>(sboxes)[cnt] = b;
        sarea[cnt] = (b.z - b.x) * (b.w - b.y);
    }
}

// NMS pair bitmask, transposed: maskT[w][i] bit jb = (IoU(i, w*64+jb) > T && j > i)
__global__ __launch_bounds__(256) void k_maskfill(const float* __restrict__ sboxes,
                                                  const float* __restrict__ sarea,
                                                  U64* __restrict__ maskT) {
    int w = blockIdx.y;
    int i0 = blockIdx.x * 256;
    if (w < (i0 >> 6)) return;
    __shared__ float4 sb[64];
    __shared__ float sa[64];
    int t = threadIdx.x;
    if (t < 64) {
        int j = w * 64 + t;
        if (j < NBOX) {
            sb[t] = reinterpret_cast<const float4*>(sboxes)[j];
            sa[t] = sarea[j];
        } else {
            sb[t] = make_float4(0.f, 0.f, 0.f, 0.f);
            sa[t] = 0.f;
        }
    }
    __syncthreads();
    int i = i0 + t;
    if (i >= NBOX || w < (i >> 6)) return;
    float4 bi = reinterpret_cast<const float4*>(sboxes)[i];
    float ai = sarea[i];
    U64 word = 0;
#pragma unroll 4
    for (int jb = 0; jb < 64; ++jb) {
        int j = w * 64 + jb;
        float4 bj = sb[jb];
        float xx1 = fmaxf(bi.x, bj.x), yy1 = fmaxf(bi.y, bj.y);
        float xx2 = fminf(bi.z, bj.z), yy2 = fminf(bi.w, bj.w);
        float inter = fmaxf(xx2 - xx1, 0.f) * fmaxf(yy2 - yy1, 0.f);
        float iou = inter / (ai + sa[jb] - inter);
        word |= ((U64)((iou > NMS_T) && (j > i))) << jb;
    }
    maskT[(size_t)w * PITCH + i] = word;  // coalesced across threads
}

// exact greedy sweep: kept-only readlane resolve + diag prefetch + klist cross-OR
__global__ __launch_bounds__(256) void k_sweep(const U64* __restrict__ maskT,
                                               const float* __restrict__ sboxes,
                                               float* __restrict__ rois_out,
                                               float* __restrict__ keep_out) {
    __shared__ U64 rem[NW];
    __shared__ U64 diag[2][64];
    __shared__ int klist[64];
    __shared__ unsigned base_s;
    int t = threadIdx.x;
    for (int u = t; u < NW; u += 256) rem[u] = 0;
    if (t == 0) base_s = 0;
    if (t < 64) diag[0][t] = maskT[t];  // group 0 diag (coalesced)
    __syncthreads();

    for (int g = 0; g < NW; ++g) {
        int nv = min(64, NBOX - g * 64);
        U64 vmask = (nv == 64) ? ~0ull : ((1ull << nv) - 1);

        // (A) prefetch next diagonal block (contiguous; hidden under resolve+OR)
        U64 nxtval = 0;
        if (t < 64 && g + 1 < NW) {
            int row = (g + 1) * 64 + t;
            if (row < NBOX) nxtval = maskT[(size_t)(g + 1) * PITCH + row];
        }

        // (B) kept-only greedy resolve: iterations == kept count, readlane is cheap VALU
        U64 myw = diag[g & 1][t & 63];
        U64 notsup = ~rem[g] & vmask;
        U64 kept = 0;
        while (notsup) {
            int i = (int)__builtin_ctzll(notsup);
            kept |= (1ull << i);
            U64 wi = rdlane64(myw, i);
            notsup &= ~(wi | (1ull << i));
        }
        int nk = __popcll(kept);
        unsigned base = base_s;

        // (C) outputs + klist
        if (t < 64) {
            if ((kept >> t) & 1ull) {
                unsigned pre = (unsigned)__popcll(kept & ((1ull << t) - 1));
                unsigned dst = base + pre;
                float4 bb = reinterpret_cast<const float4*>(sboxes)[g * 64 + t];
                reinterpret_cast<float4*>(rois_out)[dst] = bb;
                keep_out[dst] = 1.0f;
                klist[pre] = t;
            }
        }
        __syncthreads();   // klist visible; base_s read by all

        if (t == 0) base_s = base + (unsigned)nk;

        // (D) cross-group OR: thread t owns word w; sparse gather of kept rows
        for (int w = g + 1 + t; w < NW; w += 256) {
            const U64* col = maskT + (size_t)w * PITCH + g * 64;
            U64 acc = rem[w];
            int b = 0;
            for (; b + 3 < nk; b += 4) {
                U64 v0 = col[klist[b]];
                U64 v1 = col[klist[b + 1]];
                U64 v2 = col[klist[b + 2]];
                U64 v3 = col[klist[b + 3]];
                acc |= v0 | v1 | v2 | v3;
            }
            for (; b < nk; ++b) acc |= col[klist[b]];
            rem[w] = acc;
        }
        if (t < 64) diag[(g + 1) & 1][t] = nxtval;
        __syncthreads();
    }
}

// ---------------- launch ----------------
extern "C" void kernel_launch(void* const* d_in, const int* in_sizes, int n_in,
                              void* d_out, int out_size, void* d_ws, size_t ws_size,
                              hipStream_t stream) {
    const float* fm      = (const float*)d_in[0];
    const float* conv_w  = (const float*)d_in[2];
    const float* conv_b  = (const float*)d_in[3];
    const float* score_w = (const float*)d_in[4];
    const float* score_b = (const float*)d_in[5];
    const float* loc_w   = (const float*)d_in[6];
    const float* loc_b   = (const float*)d_in[7];

    float* out = (float*)d_out;
    float* rois_out  = out;
    float* keep_out  = out + NBOX * 4;
    float* anch_out  = out + NBOX * 5;
    float* loc_out   = out + NBOX * 9;
    float* score_out = out + NBOX * 13;

    if (ws_size < WS_NEED) {
        k_sentinel<<<(out_size + 255) / 256, 256, 0, stream>>>(out, out_size);
        return;
    }

    char* ws = (char*)d_ws;
    float* in_t    = (float*)(ws + OFF_INT);
    float* wt      = (float*)(ws + OFF_WT);
    float* partial = (float*)(ws + OFF_PART);
    U64*   maskT   = (U64*)(ws + OFF_MASK);
    float* mid     = (float*)(ws + OFF_MID);
    float* fg      = (float*)(ws + OFF_FG);
    float* boxes   = (float*)(ws + OFF_BOX);
    float* sboxes  = (float*)(ws + OFF_SBOX);
    float* sarea   = (float*)(ws + OFF_SAREA);

    hipMemsetAsync(in_t, 0, SZ_INT, stream);
    k_in_t<<<dim3(H, CIN / 64), 256, 0, stream>>>(fm, in_t);
    k_w_t<<<dim3(CIN * 9 / 64, CMID / 64), 256, 0, stream>>>(conv_w, wt);
    k_conv<<<dim3(QTILES, 8, KS), 256, 0, stream>>>(in_t, wt, partial);
    k_reduce<<<P, 256, 0, stream>>>(partial, conv_b, mid);
    k_heads<<<P / 4, 256, 0, stream>>>(mid, score_w, score_b, loc_w, loc_b,
                                       score_out, loc_out, anch_out, fg, boxes);
    k_rank<<<(NBOX + 255) / 256, 256, 0, stream>>>(fg, boxes, sboxes, sarea);
    hipMemsetAsync(rois_out, 0, (size_t)NBOX * 5 * 4, stream);  // rois_out + keep
    k_maskfill<<<dim3((NBOX + 255) / 256, NW), 256, 0, stream>>>(sboxes, sarea, maskT);
    k_sweep<<<1, 256, 0, stream>>>(maskT, sboxes, rois_out, keep_out);
}

// Round 4
// 921.064 us; speedup vs baseline: 2.0171x; 1.5198x over previous
//
#include <hip/hip_runtime.h>
#include <cstdint>

#define U64 unsigned long long

static constexpr int H = 38, W = 50, P = 1900;        // feature map
static constexpr int CIN = 2048, CMID = 256;
static constexpr int NA = 9, NBOX = 17100;            // 1900*9
static constexpr int HP = 40, WP = 52, QP = HP * WP;  // padded positions (2080)
static constexpr int TPITCH = 2084;                   // in_tT row pitch (floats), mult of 4
static constexpr int KS = 7, CHUNK = 304;             // split-K over cin
static constexpr int NW = 268;                        // u64 words covering NBOX bits
static constexpr int PITCH = 17152;                   // maskT row pitch (words)
static constexpr float NMS_T = 0.5f;
static constexpr int QTILE = 256;
static constexpr int QTILES = 9;                      // 9*256 = 2304 >= QP
static constexpr int SIN_STRIDE = 372;                // s_in row stride (floats), mult of 4

// ---------------- ws layout (bytes) ----------------
static constexpr size_t SZ_INT  = (size_t)CIN * TPITCH * 4;   // 17,072,128
static constexpr size_t SZ_WT   = (size_t)9 * CIN * CMID * 4; // 18,874,368
static constexpr size_t SZ_PART = (size_t)KS * P * CMID * 4;  // 13,619,200
static constexpr size_t OFF_INT  = 0;
static constexpr size_t OFF_WT   = OFF_INT + SZ_INT;
static constexpr size_t OFF_PART = OFF_WT + SZ_WT;
static constexpr size_t REGA     = OFF_PART + SZ_PART;        // 49,565,696
static constexpr size_t OFF_MASK = 0;                          // maskT overlays region A (dead)
static constexpr size_t OFF_MID  = REGA;
static constexpr size_t OFF_FG   = OFF_MID + 1945600;
static constexpr size_t OFF_BOX  = OFF_FG + 68608;
static constexpr size_t OFF_SBOX = OFF_BOX + 273664;
static constexpr size_t OFF_SAREA= OFF_SBOX + 273664;
static constexpr size_t OFF_CNT  = OFF_SAREA + 68608;
static constexpr size_t WS_NEED  = OFF_CNT + 68608;            // ~52.26 MB

__device__ __forceinline__ U64 rdlane64(U64 v, int l) {
    unsigned lo = (unsigned)__builtin_amdgcn_readlane((int)(unsigned)(v & 0xffffffffull), l);
    unsigned hi = (unsigned)__builtin_amdgcn_readlane((int)(unsigned)(v >> 32), l);
    return ((U64)hi << 32) | (U64)lo;
}

// ---------------- kernels ----------------

__global__ __launch_bounds__(256) void k_sentinel(float* out, int n) {
    int i = blockIdx.x * 256 + threadIdx.x;
    if (i < n) out[i] = 1.2345678e8f;
}

// feature_map [CIN][H][W] -> in_tT [CIN][TPITCH] (padded image rows; memset first)
__global__ __launch_bounds__(256) void k_in_t(const float* __restrict__ fm, float* __restrict__ in_tT) {
    int idx = blockIdx.x * 256 + threadIdx.x;
    if (idx >= CIN * (H * W)) return;
    int ci = idx / (H * W), hw = idx - ci * (H * W);
    int h = hw / W, w = hw - h * W;
    in_tT[(size_t)ci * TPITCH + (h + 1) * WP + 1 + w] = fm[idx];
}

// conv_w [CMID][CIN][3][3] -> w_t [9][CIN][CMID]
__global__ __launch_bounds__(256) void k_w_t(const float* __restrict__ cw, float* __restrict__ wt) {
    __shared__ float tl[64][65];
    int x0 = blockIdx.x * 64, c0 = blockIdx.y * 64, t = threadIdx.x;
    for (int rep = 0; rep < 16; ++rep) {
        int lin = rep * 256 + t;
        int row = lin / 64, col = lin % 64;
        tl[row][col] = cw[(size_t)(c0 + row) * (CIN * 9) + x0 + col];
    }
    __syncthreads();
    for (int rep = 0; rep < 16; ++rep) {
        int lin = rep * 256 + t;
        int xr = lin / 64, cr = lin % 64;
        int x = x0 + xr;
        int k = x % 9, cin = x / 9;
        wt[((size_t)k * CIN + cin) * CMID + c0 + cr] = tl[cr][xr];
    }
}

// 3x3 conv, split-K. grid (9 q-tiles of 256, 8 cout-groups of 32, KS)
// thread: 4 q (stride 64) x 8 cout. LDS: s_in [16][372], s_w [16][9][32].
__global__ __launch_bounds__(256) void k_conv(const float* __restrict__ in_tT,
                                              const float* __restrict__ wt,
                                              float* __restrict__ partial) {
    __shared__ float s_in[16 * SIN_STRIDE];
    __shared__ float s_w[16 * 9 * 32];
    int t = threadIdx.x;
    int tq = t & 63;            // q lane
    int sub = t >> 6;           // wave id -> cout sub-block of 8 (wave-uniform)
    int q0 = blockIdx.x * QTILE;
    int cout0 = blockIdx.y * 32;
    int cin0 = blockIdx.z * CHUNK;
    int cin1 = min(CIN, cin0 + CHUNK);
    float acc[4][8];
#pragma unroll
    for (int j = 0; j < 4; ++j)
#pragma unroll
        for (int c = 0; c < 8; ++c) acc[j][c] = 0.f;

    for (int c0 = cin0; c0 < cin1; c0 += 16) {
        // stage input rows: x in [0,368), q = q0-56+x (4-aligned float4 loads, coalesced)
        for (int idx = t; idx < 16 * 92; idx += 256) {
            int ci = idx / 92, xi = idx - ci * 92;
            int q = q0 - 56 + xi * 4;
            float4 v = make_float4(0.f, 0.f, 0.f, 0.f);
            if (q >= 0 && q <= QP)   // q==QP reads row pad zeros
                v = *reinterpret_cast<const float4*>(in_tT + (size_t)(c0 + ci) * TPITCH + q);
            *reinterpret_cast<float4*>(s_in + ci * SIN_STRIDE + xi * 4) = v;
        }
        // stage weights: [ci][k][32] float4
        for (int idx = t; idx < 1152; idx += 256) {
            int c4 = idx & 7, r = idx >> 3;
            int ci = r / 9, k = r - ci * 9;
            float4 v = *reinterpret_cast<const float4*>(
                wt + ((size_t)k * CIN + c0 + ci) * CMID + cout0 + c4 * 4);
            reinterpret_cast<float4*>(s_w)[r * 8 + c4] = v;
        }
        __syncthreads();
#pragma unroll 1
        for (int ci = 0; ci < 16; ++ci) {
            const float* si = s_in + ci * SIN_STRIDE + tq + 56;
            const float* swb = s_w + ci * 288 + sub * 8;
#pragma unroll
            for (int k = 0; k < 9; ++k) {
                const int DQ[9] = {-53, -52, -51, -1, 0, 1, 51, 52, 53};
                float ivv[4];
#pragma unroll
                for (int j = 0; j < 4; ++j) ivv[j] = si[DQ[k] + 64 * j];
                float4 wa = *reinterpret_cast<const float4*>(swb + k * 32);
                float4 wb = *reinterpret_cast<const float4*>(swb + k * 32 + 4);
                float wv[8] = {wa.x, wa.y, wa.z, wa.w, wb.x, wb.y, wb.z, wb.w};
#pragma unroll
                for (int j = 0; j < 4; ++j)
#pragma unroll
                    for (int c = 0; c < 8; ++c) acc[j][c] += ivv[j] * wv[c];
            }
        }
        __syncthreads();
    }
    float* part = partial + (size_t)blockIdx.z * P * CMID;
#pragma unroll
    for (int j = 0; j < 4; ++j) {
        int q = q0 + tq + 64 * j;
        if (q < QP) {
            int hp = q / WP, wp_ = q - hp * WP;
            if (hp >= 1 && hp <= H && wp_ >= 1 && wp_ <= W) {
                int p = (hp - 1) * W + (wp_ - 1);
                float* dst = part + (size_t)p * CMID + cout0 + sub * 8;
                float4* d4 = reinterpret_cast<float4*>(dst);
                d4[0] = make_float4(acc[j][0], acc[j][1], acc[j][2], acc[j][3]);
                d4[1] = make_float4(acc[j][4], acc[j][5], acc[j][6], acc[j][7]);
            }
        }
    }
}

// sum partials + bias + relu -> mid [P][CMID]
__global__ __launch_bounds__(256) void k_reduce(const float* __restrict__ partial,
                                                const float* __restrict__ bias,
                                                float* __restrict__ mid) {
    int p = blockIdx.x, c = threadIdx.x;
    float s = bias[c];
    for (int ks = 0; ks < KS; ++ks) s += partial[(size_t)ks * P * CMID + (size_t)p * CMID + c];
    mid[(size_t)p * CMID + c] = fmaxf(s, 0.f);
}

// 1x1 heads + softmax + anchors + loc2bbox + clip. 16 positions per block (4 reps).
__global__ __launch_bounds__(256) void k_heads(const float* __restrict__ mid,
                                               const float* __restrict__ score_w,
                                               const float* __restrict__ score_b,
                                               const float* __restrict__ loc_w,
                                               const float* __restrict__ loc_b,
                                               float* __restrict__ score_out,
                                               float* __restrict__ loc_out,
                                               float* __restrict__ anch_out,
                                               float* __restrict__ fg,
                                               float* __restrict__ boxes) {
    __shared__ float wl[256][56];
    __shared__ float bias[56];
    __shared__ float dots[4][64];
    int t = threadIdx.x;
    for (int idx = t; idx < 18 * 256; idx += 256) {
        int c = idx >> 8, i = idx & 255;
        wl[i][c] = score_w[idx];
    }
    for (int idx = t; idx < 36 * 256; idx += 256) {
        int c = idx >> 8, i = idx & 255;
        wl[i][18 + c] = loc_w[idx];
    }
    if (t < 18) bias[t] = score_b[t];
    else if (t < 54) bias[t] = loc_b[t - 18];
    __syncthreads();

    int pl = t >> 6, c = t & 63;
    for (int rep = 0; rep < 4; ++rep) {
        int p = blockIdx.x * 16 + rep * 4 + pl;
        if (c < 54 && p < P) {
            float d = bias[c];
            const float4* mp = reinterpret_cast<const float4*>(mid + (size_t)p * CMID);
            for (int i4 = 0; i4 < 64; ++i4) {
                float4 m4 = mp[i4];
                int i = i4 * 4;
                d += m4.x * wl[i][c] + m4.y * wl[i + 1][c] + m4.z * wl[i + 2][c] + m4.w * wl[i + 3][c];
            }
            dots[pl][c] = d;
        }
        __syncthreads();
        if (c < NA && p < P) {
            int a = c;
            int idx = p * NA + a;
            float l0 = dots[pl][2 * a], l1 = dots[pl][2 * a + 1];
            float mx = fmaxf(l0, l1);
            float e0 = expf(l0 - mx), e1 = expf(l1 - mx);
            float den = e0 + e1;
            float s0 = e0 / den, s1 = e1 / den;
            score_out[(size_t)idx * 2 + 0] = s0;
            score_out[(size_t)idx * 2 + 1] = s1;
            fg[idx] = s1;
            float dx = dots[pl][18 + 4 * a + 0];
            float dy = dots[pl][18 + 4 * a + 1];
            float dw = dots[pl][18 + 4 * a + 2];
            float dh = dots[pl][18 + 4 * a + 3];
            loc_out[(size_t)idx * 4 + 0] = dx;
            loc_out[(size_t)idx * 4 + 1] = dy;
            loc_out[(size_t)idx * 4 + 2] = dw;
            loc_out[(size_t)idx * 4 + 3] = dh;
            int hh = p / W, ww = p % W;
            const double scales[3] = {8.0, 16.0, 32.0};
            const double ratios[3] = {0.5, 1.0, 2.0};
            double s = scales[a / 3], r = ratios[a % 3];
            double wb2 = 16.0 * s * sqrt(r);
            double hb = wb2 / r;
            double xmin = 8.0 - wb2 / 2.0, ymin = 8.0 - hb / 2.0;
            float b0 = (float)xmin, b1 = (float)ymin;
            float b2 = (float)(xmin + wb2), b3 = (float)(ymin + hb);
            float gx = (float)(ww * 16), gy = (float)(hh * 16);
            float a0 = gx + b0, a1 = gy + b1, a2 = gx + b2, a3 = gy + b3;
            anch_out[(size_t)idx * 4 + 0] = a0;
            anch_out[(size_t)idx * 4 + 1] = a1;
            anch_out[(size_t)idx * 4 + 2] = a2;
            anch_out[(size_t)idx * 4 + 3] = a3;
            float aw = a2 - a0, ah = a3 - a1;
            float cx = a0 + 0.5f * aw, cy = a1 + 0.5f * ah;
            float ncx = dx * aw + cx, ncy = dy * ah + cy;
            float nw = expf(dw) * aw, nh = expf(dh) * ah;
            float x1 = ncx - 0.5f * nw, y1 = ncy - 0.5f * nh;
            float x2 = ncx + 0.5f * nw, y2 = ncy + 0.5f * nh;
            x1 = fminf(fmaxf(x1, 0.f), (float)(W * 16));
            x2 = fminf(fmaxf(x2, 0.f), (float)(W * 16));
            y1 = fminf(fmaxf(y1, 0.f), (float)(H * 16));
            y2 = fminf(fmaxf(y2, 0.f), (float)(H * 16));
            float4* bp = reinterpret_cast<float4*>(boxes);
            bp[idx] = make_float4(x1, y1, x2, y2);
        }
        __syncthreads();
    }
}

// partial stable-descending rank counts over a j-slice. grid (67, 8)
static constexpr int JSL = 2144;  // slice size (mult of 4)
__global__ __launch_bounds__(256) void k_rank_part(const float* __restrict__ fg,
                                                   int* __restrict__ cntb) {
    __shared__ float4 tile[256];
    int t = threadIdx.x;
    int i = blockIdx.x * 256 + t;
    int j0 = blockIdx.y * JSL;
    int j1 = min(NBOX, j0 + JSL);
    float my = (i < NBOX) ? fg[i] : 0.f;
    int cnt = 0;
    for (int base = j0; base < j1; base += 1024) {
        int j = base + t * 4;
        float4 v = make_float4(-3.4e38f, -3.4e38f, -3.4e38f, -3.4e38f);
        if (j + 3 < j1) {
            v = *reinterpret_cast<const float4*>(fg + j);
        } else {
            if (j < j1) v.x = fg[j];
            if (j + 1 < j1) v.y = fg[j + 1];
            if (j + 2 < j1) v.z = fg[j + 2];
            if (j + 3 < j1) v.w = fg[j + 3];
        }
        __syncthreads();
        tile[t] = v;
        __syncthreads();
        if (i < NBOX) {
            for (int u = 0; u < 256; ++u) {
                float4 s = tile[u];
                int jb = base + u * 4;
                cnt += (s.x > my) || (s.x == my && jb < i);
                cnt += (s.y > my) || (s.y == my && jb + 1 < i);
                cnt += (s.z > my) || (s.z == my && jb + 2 < i);
                cnt += (s.w > my) || (s.w == my && jb + 3 < i);
            }
        }
    }
    if (i < NBOX && cnt) atomicAdd(&cntb[i], cnt);
}

// scatter boxes to sorted order using rank counts
__global__ __launch_bounds__(256) void k_scatter(const int* __restrict__ cntb,
                                                 const float* __restrict__ boxes,
                                                 float* __restrict__ sboxes,
                                                 float* __restrict__ sarea) {
    int i = blockIdx.x * 256 + threadIdx.x;
    if (i >= NBOX) return;
    int c = cntb[i];
    float4 b = reinterpret_cast<const float4*>(boxes)[i];
    reinterpret_cast<float4*>(sboxes)[c] = b;
    sarea[c] = (b.z - b.x) * (b.w - b.y);
}

// NMS pair bitmask, transposed: maskT[w][i] bit jb = (IoU(i, w*64+jb) > T && j > i)
__global__ __launch_bounds__(256) void k_maskfill(const float* __restrict__ sboxes,
                                                  const float* __restrict__ sarea,
                                                  U64* __restrict__ maskT) {
    int w = blockIdx.y;
    int i0 = blockIdx.x * 256;
    if (w < (i0 >> 6)) return;
    __shared__ float4 sb[64];
    __shared__ float sa[64];
    int t = threadIdx.x;
    if (t < 64) {
        int j = w * 64 + t;
        if (j < NBOX) {
            sb[t] = reinterpret_cast<const float4*>(sboxes)[j];
            sa[t] = sarea[j];
        } else {
            sb[t] = make_float4(0.f, 0.f, 0.f, 0.f);
            sa[t] = 0.f;
        }
    }
    __syncthreads();
    int i = i0 + t;
    if (i >= NBOX || w < (i >> 6)) return;
    float4 bi = reinterpret_cast<const float4*>(sboxes)[i];
    float ai = sarea[i];
    U64 word = 0;
#pragma unroll 4
    for (int jb = 0; jb < 64; ++jb) {
        int j = w * 64 + jb;
        float4 bj = sb[jb];
        float xx1 = fmaxf(bi.x, bj.x), yy1 = fmaxf(bi.y, bj.y);
        float xx2 = fminf(bi.z, bj.z), yy2 = fminf(bi.w, bj.w);
        float inter = fmaxf(xx2 - xx1, 0.f) * fmaxf(yy2 - yy1, 0.f);
        float iou = inter / (ai + sa[jb] - inter);
        word |= ((U64)((iou > NMS_T) && (j > i))) << jb;
    }
    maskT[(size_t)w * PITCH + i] = word;
}

// exact greedy sweep: kept-only readlane resolve + diag prefetch + klist cross-OR
__global__ __launch_bounds__(256) void k_sweep(const U64* __restrict__ maskT,
                                               const float* __restrict__ sboxes,
                                               float* __restrict__ rois_out,
                                               float* __restrict__ keep_out) {
    __shared__ U64 rem[NW];
    __shared__ U64 diag[2][64];
    __shared__ int klist[64];
    __shared__ unsigned base_s;
    int t = threadIdx.x;
    for (int u = t; u < NW; u += 256) rem[u] = 0;
    if (t == 0) base_s = 0;
    if (t < 64) diag[0][t] = maskT[t];
    __syncthreads();

    for (int g = 0; g < NW; ++g) {
        int nv = min(64, NBOX - g * 64);
        U64 vmask = (nv == 64) ? ~0ull : ((1ull << nv) - 1);

        U64 nxtval = 0;
        if (t < 64 && g + 1 < NW) {
            int row = (g + 1) * 64 + t;
            if (row < NBOX) nxtval = maskT[(size_t)(g + 1) * PITCH + row];
        }

        U64 myw = diag[g & 1][t & 63];
        U64 notsup = ~rem[g] & vmask;
        U64 kept = 0;
        while (notsup) {
            int i = (int)__builtin_ctzll(notsup);
            kept |= (1ull << i);
            U64 wi = rdlane64(myw, i);
            notsup &= ~(wi | (1ull << i));
        }
        int nk = __popcll(kept);
        unsigned base = base_s;

        if (t < 64) {
            if ((kept >> t) & 1ull) {
                unsigned pre = (unsigned)__popcll(kept & ((1ull << t) - 1));
                unsigned dst = base + pre;
                float4 bb = reinterpret_cast<const float4*>(sboxes)[g * 64 + t];
                reinterpret_cast<float4*>(rois_out)[dst] = bb;
                keep_out[dst] = 1.0f;
                klist[pre] = t;
            }
        }
        __syncthreads();

        if (t == 0) base_s = base + (unsigned)nk;

        for (int w = g + 1 + t; w < NW; w += 256) {
            const U64* col = maskT + (size_t)w * PITCH + g * 64;
            U64 acc = rem[w];
            int b = 0;
            for (; b + 7 < nk; b += 8) {
                U64 v0 = col[klist[b]];
                U64 v1 = col[klist[b + 1]];
                U64 v2 = col[klist[b + 2]];
                U64 v3 = col[klist[b + 3]];
                U64 v4 = col[klist[b + 4]];
                U64 v5 = col[klist[b + 5]];
                U64 v6 = col[klist[b + 6]];
                U64 v7 = col[klist[b + 7]];
                acc |= v0 | v1 | v2 | v3 | v4 | v5 | v6 | v7;
            }
            for (; b + 3 < nk; b += 4) {
                U64 v0 = col[klist[b]];
                U64 v1 = col[klist[b + 1]];
                U64 v2 = col[klist[b + 2]];
                U64 v3 = col[klist[b + 3]];
                acc |= v0 | v1 | v2 | v3;
            }
            for (; b < nk; ++b) acc |= col[klist[b]];
            rem[w] = acc;
        }
        if (t < 64) diag[(g + 1) & 1][t] = nxtval;
        __syncthreads();
    }
}

// ---------------- launch ----------------
extern "C" void kernel_launch(void* const* d_in, const int* in_sizes, int n_in,
                              void* d_out, int out_size, void* d_ws, size_t ws_size,
                              hipStream_t stream) {
    const float* fm      = (const float*)d_in[0];
    const float* conv_w  = (const float*)d_in[2];
    const float* conv_b  = (const float*)d_in[3];
    const float* score_w = (const float*)d_in[4];
    const float* score_b = (const float*)d_in[5];
    const float* loc_w   = (const float*)d_in[6];
    const float* loc_b   = (const float*)d_in[7];

    float* out = (float*)d_out;
    float* rois_out  = out;
    float* keep_out  = out + NBOX * 4;
    float* anch_out  = out + NBOX * 5;
    float* loc_out   = out + NBOX * 9;
    float* score_out = out + NBOX * 13;

    if (ws_size < WS_NEED) {
        k_sentinel<<<(out_size + 255) / 256, 256, 0, stream>>>(out, out_size);
        return;
    }

    char* ws = (char*)d_ws;
    float* in_tT   = (float*)(ws + OFF_INT);
    float* wt      = (float*)(ws + OFF_WT);
    float* partial = (float*)(ws + OFF_PART);
    U64*   maskT   = (U64*)(ws + OFF_MASK);
    float* mid     = (float*)(ws + OFF_MID);
    float* fg      = (float*)(ws + OFF_FG);
    float* boxes   = (float*)(ws + OFF_BOX);
    float* sboxes  = (float*)(ws + OFF_SBOX);
    float* sarea   = (float*)(ws + OFF_SAREA);
    int*   cntb    = (int*)(ws + OFF_CNT);

    hipMemsetAsync(in_tT, 0, SZ_INT, stream);
    k_in_t<<<(CIN * H * W + 255) / 256, 256, 0, stream>>>(fm, in_tT);
    k_w_t<<<dim3(CIN * 9 / 64, CMID / 64), 256, 0, stream>>>(conv_w, wt);
    k_conv<<<dim3(QTILES, 8, KS), 256, 0, stream>>>(in_tT, wt, partial);
    k_reduce<<<P, 256, 0, stream>>>(partial, conv_b, mid);
    k_heads<<<(P + 15) / 16, 256, 0, stream>>>(mid, score_w, score_b, loc_w, loc_b,
                                               score_out, loc_out, anch_out, fg, boxes);
    hipMemsetAsync(cntb, 0, NBOX * 4, stream);
    k_rank_part<<<dim3((NBOX + 255) / 256, 8), 256, 0, stream>>>(fg, cntb);
    k_scatter<<<(NBOX + 255) / 256, 256, 0, stream>>>(cntb, boxes, sboxes, sarea);
    hipMemsetAsync(rois_out, 0, (size_t)NBOX * 5 * 4, stream);  // rois_out + keep
    k_maskfill<<<dim3((NBOX + 255) / 256, NW), 256, 0, stream>>>(sboxes, sarea, maskT);
    k_sweep<<<1, 256, 0, stream>>>(maskT, sboxes, rois_out, keep_out);
}

// Round 5
// 867.897 us; speedup vs baseline: 2.1406x; 1.0613x over previous
//
#include <hip/hip_runtime.h>
#include <cstdint>

#define U64 unsigned long long

static constexpr int H = 38, W = 50, P = 1900;        // feature map
static constexpr int CIN = 2048, CMID = 256;
static constexpr int NA = 9, NBOX = 17100;            // 1900*9
static constexpr int HP = 40, WP = 52, QP = HP * WP;  // padded positions (2080)
static constexpr int TPITCH = 2084;                   // in_tT row pitch (floats), mult of 4
static constexpr int KS = 7;                          // split-K over cin
static constexpr int NW = 268;                        // u64 words covering NBOX bits
static constexpr int PITCH = 17152;                   // maskT row pitch (words)
static constexpr float NMS_T = 0.5f;
static constexpr int QTILE = 256;

// ---------------- ws layout (bytes) ----------------
static constexpr size_t SZ_INT  = (size_t)CIN * TPITCH * 4;   // 17,072,128
static constexpr size_t SZ_WT   = (size_t)9 * CIN * CMID * 4; // 18,874,368
static constexpr size_t SZ_PART = (size_t)KS * P * CMID * 4;  // 13,619,200
static constexpr size_t OFF_INT  = 0;
static constexpr size_t OFF_WT   = OFF_INT + SZ_INT;
static constexpr size_t OFF_PART = OFF_WT + SZ_WT;
static constexpr size_t REGA     = OFF_PART + SZ_PART;        // 49,565,696
static constexpr size_t OFF_MASK = 0;                          // maskT overlays region A (dead)
static constexpr size_t OFF_MID  = REGA;
static constexpr size_t OFF_FG   = OFF_MID + 1945600;
static constexpr size_t OFF_BOX  = OFF_FG + 68608;
static constexpr size_t OFF_SBOX = OFF_BOX + 273664;
static constexpr size_t OFF_SAREA= OFF_SBOX + 273664;
static constexpr size_t OFF_CNT  = OFF_SAREA + 68608;
static constexpr size_t WS_NEED  = OFF_CNT + 68608;            // ~52.26 MB (round-4 verified fits)

__device__ __forceinline__ U64 rdlane64(U64 v, int l) {
    unsigned lo = (unsigned)__builtin_amdgcn_readlane((int)(unsigned)(v & 0xffffffffull), l);
    unsigned hi = (unsigned)__builtin_amdgcn_readlane((int)(unsigned)(v >> 32), l);
    return ((U64)hi << 32) | (U64)lo;
}

// ---------------- kernels ----------------

__global__ __launch_bounds__(256) void k_sentinel(float* out, int n) {
    int i = blockIdx.x * 256 + threadIdx.x;
    if (i < n) out[i] = 1.2345678e8f;
}

// feature_map [CIN][H][W] -> in_tT [CIN][TPITCH] (padded image rows; memset first)
__global__ __launch_bounds__(256) void k_in_t(const float* __restrict__ fm, float* __restrict__ in_tT) {
    int idx = blockIdx.x * 256 + threadIdx.x;
    if (idx >= CIN * (H * W)) return;
    int ci = idx / (H * W), hw = idx - ci * (H * W);
    int h = hw / W, w = hw - h * W;
    in_tT[(size_t)ci * TPITCH + (h + 1) * WP + 1 + w] = fm[idx];
}

// conv_w [CMID][CIN][3][3] -> w2 [y(8)][sub(4)][ci(2048)][k(9)][c(8)]
__global__ __launch_bounds__(256) void k_w_t(const float* __restrict__ cw, float* __restrict__ w2) {
    int idx = blockIdx.x * 256 + threadIdx.x;
    if (idx >= CMID * CIN * 9) return;
    int co = idx / (CIN * 9);
    int rem = idx - co * (CIN * 9);
    int ci = rem / 9, k = rem - ci * 9;
    w2[((size_t)(co >> 3) * CIN + ci) * 72 + k * 8 + (co & 7)] = cw[idx];
}

// 3x3 conv, split-K. grid 504 = 9 qtiles x 8 cout-groups x 7 z (XCD-swizzled).
// lane owns 4 contiguous q; wave covers 256 q x 8 cout. Input via skewed-b128 LDS,
// weights via wave-uniform global reads (no LDS).
__global__ __launch_bounds__(256, 2) void k_conv(const float* __restrict__ in_tT,
                                                 const float* __restrict__ w2,
                                                 float* __restrict__ partial) {
    __shared__ float4 s_in4[16 * 104];   // 16 ci x 104 skewed quads (26.6 KB)
    int t = threadIdx.x;
    int lane = t & 63;
    int sub = __builtin_amdgcn_readfirstlane(t >> 6);   // wave-uniform SGPR

    // XCD-aware swizzle: z-major so blocks sharing a z-slice share an L2
    int raw = blockIdx.x;
    int xcd = raw & 7, i0 = raw >> 3;
    int L = xcd * 63 + i0;          // 504 = 8*63, bijective
    int z = L / 72;
    int r0 = L - z * 72;
    int bx = r0 % 9, by = r0 / 9;
    int q0 = bx * QTILE;
    int cout0 = by * 32;
    int cin0 = (z <= 1) ? 304 * z : 608 + 288 * (z - 2);   // 304,304,288x5 (all mult 16)
    int cin1 = cin0 + ((z <= 1) ? 304 : 288);

    float acc[4][8];
#pragma unroll
    for (int j = 0; j < 4; ++j)
#pragma unroll
        for (int c = 0; c < 8; ++c) acc[j][c] = 0.f;

    const float* wbase = w2 + (size_t)(by * 4 + sub) * CIN * 72;

    for (int c0 = cin0; c0 < cin1; c0 += 16) {
        // stage 16 ci rows: 92 quads each, skew slot = j + (j>>3)
        for (int idx = t; idx < 16 * 92; idx += 256) {
            int r = idx / 92, j = idx - r * 92;
            int qf = q0 - 56 + 4 * j;
            float4 v = make_float4(0.f, 0.f, 0.f, 0.f);
            if (qf >= 0 && qf <= 2080)
                v = *reinterpret_cast<const float4*>(in_tT + (size_t)(c0 + r) * TPITCH + qf);
            s_in4[r * 104 + j + (j >> 3)] = v;
        }
        __syncthreads();
#pragma unroll 1
        for (int r = 0; r < 16; ++r) {
            const float4* row4 = s_in4 + r * 104;
            const float4* w4 = reinterpret_cast<const float4*>(wbase + (size_t)(c0 + r) * 72);
#pragma unroll
            for (int dy = 0; dy < 3; ++dy) {
                int v0 = lane + 13 * dy;
                int v1 = v0 + 1, v2 = v0 + 2;
                float4 F0 = row4[v0 + (v0 >> 3)];
                float4 F1 = row4[v1 + (v1 >> 3)];
                float4 F2 = row4[v2 + (v2 >> 3)];
                float F[12] = {F0.x, F0.y, F0.z, F0.w, F1.x, F1.y, F1.z, F1.w,
                               F2.x, F2.y, F2.z, F2.w};
#pragma unroll
                for (int dxi = 0; dxi < 3; ++dxi) {
                    int k = dy * 3 + dxi;
                    float4 wa = w4[k * 2], wb = w4[k * 2 + 1];
                    float wv[8] = {wa.x, wa.y, wa.z, wa.w, wb.x, wb.y, wb.z, wb.w};
#pragma unroll
                    for (int jj = 0; jj < 4; ++jj) {
                        float iv = F[jj + dxi + 3];
#pragma unroll
                        for (int c = 0; c < 8; ++c) acc[jj][c] += iv * wv[c];
                    }
                }
            }
        }
        __syncthreads();
    }
    float* part = partial + (size_t)z * P * CMID;
#pragma unroll
    for (int jj = 0; jj < 4; ++jj) {
        int q = q0 + 4 * lane + jj;
        if (q < QP) {
            int hp = q / WP, wp_ = q - hp * WP;
            if (hp >= 1 && hp <= H && wp_ >= 1 && wp_ <= W) {
                int p = (hp - 1) * W + (wp_ - 1);
                float* dst = part + (size_t)p * CMID + cout0 + sub * 8;
                float4* d4 = reinterpret_cast<float4*>(dst);
                d4[0] = make_float4(acc[jj][0], acc[jj][1], acc[jj][2], acc[jj][3]);
                d4[1] = make_float4(acc[jj][4], acc[jj][5], acc[jj][6], acc[jj][7]);
            }
        }
    }
}

// sum partials + bias + relu -> mid [P][CMID]
__global__ __launch_bounds__(256) void k_reduce(const float* __restrict__ partial,
                                                const float* __restrict__ bias,
                                                float* __restrict__ mid) {
    int p = blockIdx.x, c = threadIdx.x;
    float s = bias[c];
    for (int ks = 0; ks < KS; ++ks) s += partial[(size_t)ks * P * CMID + (size_t)p * CMID + c];
    mid[(size_t)p * CMID + c] = fmaxf(s, 0.f);
}

// 1x1 heads + softmax + anchors + loc2bbox + clip. 16 positions per block (4 reps).
__global__ __launch_bounds__(256) void k_heads(const float* __restrict__ mid,
                                               const float* __restrict__ score_w,
                                               const float* __restrict__ score_b,
                                               const float* __restrict__ loc_w,
                                               const float* __restrict__ loc_b,
                                               float* __restrict__ score_out,
                                               float* __restrict__ loc_out,
                                               float* __restrict__ anch_out,
                                               float* __restrict__ fg,
                                               float* __restrict__ boxes) {
    __shared__ float wl[256][56];
    __shared__ float bias[56];
    __shared__ float dots[4][64];
    int t = threadIdx.x;
    for (int idx = t; idx < 18 * 256; idx += 256) {
        int c = idx >> 8, i = idx & 255;
        wl[i][c] = score_w[idx];
    }
    for (int idx = t; idx < 36 * 256; idx += 256) {
        int c = idx >> 8, i = idx & 255;
        wl[i][18 + c] = loc_w[idx];
    }
    if (t < 18) bias[t] = score_b[t];
    else if (t < 54) bias[t] = loc_b[t - 18];
    __syncthreads();

    int pl = t >> 6, c = t & 63;
    for (int rep = 0; rep < 4; ++rep) {
        int p = blockIdx.x * 16 + rep * 4 + pl;
        if (c < 54 && p < P) {
            float d = bias[c];
            const float4* mp = reinterpret_cast<const float4*>(mid + (size_t)p * CMID);
            for (int i4 = 0; i4 < 64; ++i4) {
                float4 m4 = mp[i4];
                int i = i4 * 4;
                d += m4.x * wl[i][c] + m4.y * wl[i + 1][c] + m4.z * wl[i + 2][c] + m4.w * wl[i + 3][c];
            }
            dots[pl][c] = d;
        }
        __syncthreads();
        if (c < NA && p < P) {
            int a = c;
            int idx = p * NA + a;
            float l0 = dots[pl][2 * a], l1 = dots[pl][2 * a + 1];
            float mx = fmaxf(l0, l1);
            float e0 = expf(l0 - mx), e1 = expf(l1 - mx);
            float den = e0 + e1;
            float s0 = e0 / den, s1 = e1 / den;
            score_out[(size_t)idx * 2 + 0] = s0;
            score_out[(size_t)idx * 2 + 1] = s1;
            fg[idx] = s1;
            float dx = dots[pl][18 + 4 * a + 0];
            float dy = dots[pl][18 + 4 * a + 1];
            float dw = dots[pl][18 + 4 * a + 2];
            float dh = dots[pl][18 + 4 * a + 3];
            loc_out[(size_t)idx * 4 + 0] = dx;
            loc_out[(size_t)idx * 4 + 1] = dy;
            loc_out[(size_t)idx * 4 + 2] = dw;
            loc_out[(size_t)idx * 4 + 3] = dh;
            int hh = p / W, ww = p % W;
            const double scales[3] = {8.0, 16.0, 32.0};
            const double ratios[3] = {0.5, 1.0, 2.0};
            double s = scales[a / 3], r = ratios[a % 3];
            double wb2 = 16.0 * s * sqrt(r);
            double hb = wb2 / r;
            double xmin = 8.0 - wb2 / 2.0, ymin = 8.0 - hb / 2.0;
            float b0 = (float)xmin, b1 = (float)ymin;
            float b2 = (float)(xmin + wb2), b3 = (float)(ymin + hb);
            float gx = (float)(ww * 16), gy = (float)(hh * 16);
            float a0 = gx + b0, a1 = gy + b1, a2 = gx + b2, a3 = gy + b3;
            anch_out[(size_t)idx * 4 + 0] = a0;
            anch_out[(size_t)idx * 4 + 1] = a1;
            anch_out[(size_t)idx * 4 + 2] = a2;
            anch_out[(size_t)idx * 4 + 3] = a3;
            float aw = a2 - a0, ah = a3 - a1;
            float cx = a0 + 0.5f * aw, cy = a1 + 0.5f * ah;
            float ncx = dx * aw + cx, ncy = dy * ah + cy;
            float nw = expf(dw) * aw, nh = expf(dh) * ah;
            float x1 = ncx - 0.5f * nw, y1 = ncy - 0.5f * nh;
            float x2 = ncx + 0.5f * nw, y2 = ncy + 0.5f * nh;
            x1 = fminf(fmaxf(x1, 0.f), (float)(W * 16));
            x2 = fminf(fmaxf(x2, 0.f), (float)(W * 16));
            y1 = fminf(fmaxf(y1, 0.f), (float)(H * 16));
            y2 = fminf(fmaxf(y2, 0.f), (float)(H * 16));
            float4* bp = reinterpret_cast<float4*>(boxes);
            bp[idx] = make_float4(x1, y1, x2, y2);
        }
        __syncthreads();
    }
}

// partial stable-descending rank counts over a j-slice. grid (67, 8)
static constexpr int JSL = 2144;  // slice size (mult of 4)
__global__ __launch_bounds__(256) void k_rank_part(const float* __restrict__ fg,
                                                   int* __restrict__ cntb) {
    __shared__ float4 tile[256];
    int t = threadIdx.x;
    int i = blockIdx.x * 256 + t;
    int j0 = blockIdx.y * JSL;
    int j1 = min(NBOX, j0 + JSL);
    float my = (i < NBOX) ? fg[i] : 0.f;
    int cnt = 0;
    for (int base = j0; base < j1; base += 1024) {
        int j = base + t * 4;
        float4 v = make_float4(-3.4e38f, -3.4e38f, -3.4e38f, -3.4e38f);
        if (j + 3 < j1) {
            v = *reinterpret_cast<const float4*>(fg + j);
        } else {
            if (j < j1) v.x = fg[j];
            if (j + 1 < j1) v.y = fg[j + 1];
            if (j + 2 < j1) v.z = fg[j + 2];
            if (j + 3 < j1) v.w = fg[j + 3];
        }
        __syncthreads();
        tile[t] = v;
        __syncthreads();
        if (i < NBOX) {
            for (int u = 0; u < 256; ++u) {
                float4 s = tile[u];
                int jb = base + u * 4;
                cnt += (s.x > my) || (s.x == my && jb < i);
                cnt += (s.y > my) || (s.y == my && jb + 1 < i);
                cnt += (s.z > my) || (s.z == my && jb + 2 < i);
                cnt += (s.w > my) || (s.w == my && jb + 3 < i);
            }
        }
    }
    if (i < NBOX && cnt) atomicAdd(&cntb[i], cnt);
}

// scatter boxes to sorted order using rank counts
__global__ __launch_bounds__(256) void k_scatter(const int* __restrict__ cntb,
                                                 const float* __restrict__ boxes,
                                                 float* __restrict__ sboxes,
                                                 float* __restrict__ sarea) {
    int i = blockIdx.x * 256 + threadIdx.x;
    if (i >= NBOX) return;
    int c = cntb[i];
    float4 b = reinterpret_cast<const float4*>(boxes)[i];
    reinterpret_cast<float4*>(sboxes)[c] = b;
    sarea[c] = (b.z - b.x) * (b.w - b.y);
}

// NMS pair bitmask, transposed: maskT[w][i] bit jb = (IoU(i, w*64+jb) > T && j > i)
__global__ __launch_bounds__(256) void k_maskfill(const float* __restrict__ sboxes,
                                                  const float* __restrict__ sarea,
                                                  U64* __restrict__ maskT) {
    int w = blockIdx.y;
    int i0 = blockIdx.x * 256;
    if (w < (i0 >> 6)) return;
    __shared__ float4 sb[64];
    __shared__ float sa[64];
    int t = threadIdx.x;
    if (t < 64) {
        int j = w * 64 + t;
        if (j < NBOX) {
            sb[t] = reinterpret_cast<const float4*>(sboxes)[j];
            sa[t] = sarea[j];
        } else {
            sb[t] = make_float4(0.f, 0.f, 0.f, 0.f);
            sa[t] = 0.f;
        }
    }
    __syncthreads();
    int i = i0 + t;
    if (i >= NBOX || w < (i >> 6)) return;
    float4 bi = reinterpret_cast<const float4*>(sboxes)[i];
    float ai = sarea[i];
    U64 word = 0;
#pragma unroll 4
    for (int jb = 0; jb < 64; ++jb) {
        int j = w * 64 + jb;
        float4 bj = sb[jb];
        float xx1 = fmaxf(bi.x, bj.x), yy1 = fmaxf(bi.y, bj.y);
        float xx2 = fminf(bi.z, bj.z), yy2 = fminf(bi.w, bj.w);
        float inter = fmaxf(xx2 - xx1, 0.f) * fmaxf(yy2 - yy1, 0.f);
        float iou = inter / (ai + sa[jb] - inter);
        word |= ((U64)((iou > NMS_T) && (j > i))) << jb;
    }
    maskT[(size_t)w * PITCH + i] = word;
}

// exact greedy sweep: kept-only readlane resolve + diag prefetch + klist cross-OR
__global__ __launch_bounds__(256) void k_sweep(const U64* __restrict__ maskT,
                                               const float* __restrict__ sboxes,
                                               float* __restrict__ rois_out,
                                               float* __restrict__ keep_out) {
    __shared__ U64 rem[NW];
    __shared__ U64 diag[2][64];
    __shared__ int klist[64];
    __shared__ unsigned base_s;
    int t = threadIdx.x;
    for (int u = t; u < NW; u += 256) rem[u] = 0;
    if (t == 0) base_s = 0;
    if (t < 64) diag[0][t] = maskT[t];
    __syncthreads();

    for (int g = 0; g < NW; ++g) {
        int nv = min(64, NBOX - g * 64);
        U64 vmask = (nv == 64) ? ~0ull : ((1ull << nv) - 1);

        U64 nxtval = 0;
        if (t < 64 && g + 1 < NW) {
            int row = (g + 1) * 64 + t;
            if (row < NBOX) nxtval = maskT[(size_t)(g + 1) * PITCH + row];
        }

        U64 myw = diag[g & 1][t & 63];
        U64 notsup = ~rem[g] & vmask;
        U64 kept = 0;
        while (notsup) {
            int i = (int)__builtin_ctzll(notsup);
            kept |= (1ull << i);
            U64 wi = rdlane64(myw, i);
            notsup &= ~(wi | (1ull << i));
        }
        int nk = __popcll(kept);
        unsigned base = base_s;

        if (t < 64) {
            if ((kept >> t) & 1ull) {
                unsigned pre = (unsigned)__popcll(kept & ((1ull << t) - 1));
                unsigned dst = base + pre;
                float4 bb = reinterpret_cast<const float4*>(sboxes)[g * 64 + t];
                reinterpret_cast<float4*>(rois_out)[dst] = bb;
                keep_out[dst] = 1.0f;
                klist[pre] = t;
            }
        }
        __syncthreads();

        if (t == 0) base_s = base + (unsigned)nk;

        for (int w = g + 1 + t; w < NW; w += 256) {
            const U64* col = maskT + (size_t)w * PITCH + g * 64;
            U64 acc = rem[w];
            int b = 0;
            for (; b + 7 < nk; b += 8) {
                U64 v0 = col[klist[b]];
                U64 v1 = col[klist[b + 1]];
                U64 v2 = col[klist[b + 2]];
                U64 v3 = col[klist[b + 3]];
                U64 v4 = col[klist[b + 4]];
                U64 v5 = col[klist[b + 5]];
                U64 v6 = col[klist[b + 6]];
                U64 v7 = col[klist[b + 7]];
                acc |= v0 | v1 | v2 | v3 | v4 | v5 | v6 | v7;
            }
            for (; b + 3 < nk; b += 4) {
                U64 v0 = col[klist[b]];
                U64 v1 = col[klist[b + 1]];
                U64 v2 = col[klist[b + 2]];
                U64 v3 = col[klist[b + 3]];
                acc |= v0 | v1 | v2 | v3;
            }
            for (; b < nk; ++b) acc |= col[klist[b]];
            rem[w] = acc;
        }
        if (t < 64) diag[(g + 1) & 1][t] = nxtval;
        __syncthreads();
    }
}

// ---------------- launch ----------------
extern "C" void kernel_launch(void* const* d_in, const int* in_sizes, int n_in,
                              void* d_out, int out_size, void* d_ws, size_t ws_size,
                              hipStream_t stream) {
    const float* fm      = (const float*)d_in[0];
    const float* conv_w  = (const float*)d_in[2];
    const float* conv_b  = (const float*)d_in[3];
    const float* score_w = (const float*)d_in[4];
    const float* score_b = (const float*)d_in[5];
    const float* loc_w   = (const float*)d_in[6];
    const float* loc_b   = (const float*)d_in[7];

    float* out = (float*)d_out;
    float* rois_out  = out;
    float* keep_out  = out + NBOX * 4;
    float* anch_out  = out + NBOX * 5;
    float* loc_out   = out + NBOX * 9;
    float* score_out = out + NBOX * 13;

    if (ws_size < WS_NEED) {
        k_sentinel<<<(out_size + 255) / 256, 256, 0, stream>>>(out, out_size);
        return;
    }

    char* ws = (char*)d_ws;
    float* in_tT   = (float*)(ws + OFF_INT);
    float* w2      = (float*)(ws + OFF_WT);
    float* partial = (float*)(ws + OFF_PART);
    U64*   maskT   = (U64*)(ws + OFF_MASK);
    float* mid     = (float*)(ws + OFF_MID);
    float* fg      = (float*)(ws + OFF_FG);
    float* boxes   = (float*)(ws + OFF_BOX);
    float* sboxes  = (float*)(ws + OFF_SBOX);
    float* sarea   = (float*)(ws + OFF_SAREA);
    int*   cntb    = (int*)(ws + OFF_CNT);

    hipMemsetAsync(in_tT, 0, SZ_INT, stream);
    k_in_t<<<(CIN * H * W + 255) / 256, 256, 0, stream>>>(fm, in_tT);
    k_w_t<<<(CMID * CIN * 9 + 255) / 256, 256, 0, stream>>>(conv_w, w2);
    k_conv<<<504, 256, 0, stream>>>(in_tT, w2, partial);
    k_reduce<<<P, 256, 0, stream>>>(partial, conv_b, mid);
    k_heads<<<(P + 15) / 16, 256, 0, stream>>>(mid, score_w, score_b, loc_w, loc_b,
                                               score_out, loc_out, anch_out, fg, boxes);
    hipMemsetAsync(cntb, 0, NBOX * 4, stream);
    k_rank_part<<<dim3((NBOX + 255) / 256, 8), 256, 0, stream>>>(fg, cntb);
    k_scatter<<<(NBOX + 255) / 256, 256, 0, stream>>>(cntb, boxes, sboxes, sarea);
    hipMemsetAsync(rois_out, 0, (size_t)NBOX * 5 * 4, stream);  // rois_out + keep
    k_maskfill<<<dim3((NBOX + 255) / 256, NW), 256, 0, stream>>>(sboxes, sarea, maskT);
    k_sweep<<<1, 256, 0, stream>>>(maskT, sboxes, rois_out, keep_out);
}

// Round 6
// 852.538 us; speedup vs baseline: 2.1792x; 1.0180x over previous
//
#include <hip/hip_runtime.h>
#include <cstdint>

#define U64 unsigned long long

static constexpr int H = 38, W = 50, P = 1900;        // feature map
static constexpr int CIN = 2048, CMID = 256;
static constexpr int NA = 9, NBOX = 17100;            // 1900*9
static constexpr int HP = 40, WP = 52, QP = HP * WP;  // padded positions (2080)
static constexpr int TPITCH = 2084;                   // in_tT row pitch (floats), mult of 4
static constexpr int KS = 7;                          // split-K over cin
static constexpr int NW = 268;                        // u64 words covering NBOX bits
static constexpr int PITCH = 17152;                   // maskT row pitch (words)
static constexpr float NMS_T = 0.5f;
static constexpr int QTILE = 256;

// ---------------- ws layout (bytes) ----------------
static constexpr size_t SZ_INT  = (size_t)CIN * TPITCH * 4;   // 17,072,128
static constexpr size_t SZ_WT   = (size_t)9 * CIN * CMID * 4; // 18,874,368
static constexpr size_t SZ_PART = (size_t)KS * P * CMID * 4;  // 13,619,200
static constexpr size_t OFF_INT  = 0;
static constexpr size_t OFF_WT   = OFF_INT + SZ_INT;
static constexpr size_t OFF_PART = OFF_WT + SZ_WT;
static constexpr size_t REGA     = OFF_PART + SZ_PART;        // 49,565,696
static constexpr size_t OFF_MASK = 0;                          // maskT overlays region A (dead)
static constexpr size_t OFF_MID  = REGA;
static constexpr size_t OFF_FG   = OFF_MID + 1945600;
static constexpr size_t OFF_BOX  = OFF_FG + 68608;
static constexpr size_t OFF_SBOX = OFF_BOX + 273664;
static constexpr size_t OFF_SAREA= OFF_SBOX + 273664;
static constexpr size_t OFF_CNT  = OFF_SAREA + 68608;
static constexpr size_t WS_NEED  = OFF_CNT + 68608;            // ~52.26 MB

__device__ __forceinline__ U64 rdlane64(U64 v, int l) {
    unsigned lo = (unsigned)__builtin_amdgcn_readlane((int)(unsigned)(v & 0xffffffffull), l);
    unsigned hi = (unsigned)__builtin_amdgcn_readlane((int)(unsigned)(v >> 32), l);
    return ((U64)hi << 32) | (U64)lo;
}

// ---------------- kernels ----------------

__global__ __launch_bounds__(256) void k_sentinel(float* out, int n) {
    int i = blockIdx.x * 256 + threadIdx.x;
    if (i < n) out[i] = 1.2345678e8f;
}

// feature_map [CIN][H][W] -> in_tT [CIN][TPITCH] (padded image rows; memset first)
__global__ __launch_bounds__(256) void k_in_t(const float* __restrict__ fm, float* __restrict__ in_tT) {
    int idx = blockIdx.x * 256 + threadIdx.x;
    if (idx >= CIN * (H * W)) return;
    int ci = idx / (H * W), hw = idx - ci * (H * W);
    int h = hw / W, w = hw - h * W;
    in_tT[(size_t)ci * TPITCH + (h + 1) * WP + 1 + w] = fm[idx];
}

// conv_w [CMID][CIN][3][3] -> w2 [y(8)][sub(4)][ci(2048)][k(9)][c(8)]
__global__ __launch_bounds__(256) void k_w_t(const float* __restrict__ cw, float* __restrict__ w2) {
    int idx = blockIdx.x * 256 + threadIdx.x;
    if (idx >= CMID * CIN * 9) return;
    int co = idx / (CIN * 9);
    int rem = idx - co * (CIN * 9);
    int ci = rem / 9, k = rem - ci * 9;
    w2[((size_t)(co >> 3) * CIN + ci) * 72 + k * 8 + (co & 7)] = cw[idx];
}

// 3x3 conv, split-K. grid 504 = 9 qtiles x 8 cout-groups x 7 z (XCD-swizzled).
__global__ __launch_bounds__(256, 2) void k_conv(const float* __restrict__ in_tT,
                                                 const float* __restrict__ w2,
                                                 float* __restrict__ partial) {
    __shared__ float4 s_in4[16 * 104];   // 16 ci x 104 skewed quads (26.6 KB)
    int t = threadIdx.x;
    int lane = t & 63;
    int sub = __builtin_amdgcn_readfirstlane(t >> 6);   // wave-uniform SGPR

    int raw = blockIdx.x;
    int xcd = raw & 7, i0 = raw >> 3;
    int L = xcd * 63 + i0;          // 504 = 8*63, bijective
    int z = L / 72;
    int r0 = L - z * 72;
    int bx = r0 % 9, by = r0 / 9;
    int q0 = bx * QTILE;
    int cout0 = by * 32;
    int cin0 = (z <= 1) ? 304 * z : 608 + 288 * (z - 2);   // 304,304,288x5
    int cin1 = cin0 + ((z <= 1) ? 304 : 288);

    float acc[4][8];
#pragma unroll
    for (int j = 0; j < 4; ++j)
#pragma unroll
        for (int c = 0; c < 8; ++c) acc[j][c] = 0.f;

    const float* wbase = w2 + (size_t)(by * 4 + sub) * CIN * 72;

    for (int c0 = cin0; c0 < cin1; c0 += 16) {
        for (int idx = t; idx < 16 * 92; idx += 256) {
            int r = idx / 92, j = idx - r * 92;
            int qf = q0 - 56 + 4 * j;
            float4 v = make_float4(0.f, 0.f, 0.f, 0.f);
            if (qf >= 0 && qf <= 2080)
                v = *reinterpret_cast<const float4*>(in_tT + (size_t)(c0 + r) * TPITCH + qf);
            s_in4[r * 104 + j + (j >> 3)] = v;
        }
        __syncthreads();
#pragma unroll 1
        for (int r = 0; r < 16; ++r) {
            const float4* row4 = s_in4 + r * 104;
            const float4* w4 = reinterpret_cast<const float4*>(wbase + (size_t)(c0 + r) * 72);
#pragma unroll
            for (int dy = 0; dy < 3; ++dy) {
                int v0 = lane + 13 * dy;
                int v1 = v0 + 1, v2 = v0 + 2;
                float4 F0 = row4[v0 + (v0 >> 3)];
                float4 F1 = row4[v1 + (v1 >> 3)];
                float4 F2 = row4[v2 + (v2 >> 3)];
                float F[12] = {F0.x, F0.y, F0.z, F0.w, F1.x, F1.y, F1.z, F1.w,
                               F2.x, F2.y, F2.z, F2.w};
#pragma unroll
                for (int dxi = 0; dxi < 3; ++dxi) {
                    int k = dy * 3 + dxi;
                    float4 wa = w4[k * 2], wb = w4[k * 2 + 1];
                    float wv[8] = {wa.x, wa.y, wa.z, wa.w, wb.x, wb.y, wb.z, wb.w};
#pragma unroll
                    for (int jj = 0; jj < 4; ++jj) {
                        float iv = F[jj + dxi + 3];
#pragma unroll
                        for (int c = 0; c < 8; ++c) acc[jj][c] += iv * wv[c];
                    }
                }
            }
        }
        __syncthreads();
    }
    float* part = partial + (size_t)z * P * CMID;
#pragma unroll
    for (int jj = 0; jj < 4; ++jj) {
        int q = q0 + 4 * lane + jj;
        if (q < QP) {
            int hp = q / WP, wp_ = q - hp * WP;
            if (hp >= 1 && hp <= H && wp_ >= 1 && wp_ <= W) {
                int p = (hp - 1) * W + (wp_ - 1);
                float* dst = part + (size_t)p * CMID + cout0 + sub * 8;
                float4* d4 = reinterpret_cast<float4*>(dst);
                d4[0] = make_float4(acc[jj][0], acc[jj][1], acc[jj][2], acc[jj][3]);
                d4[1] = make_float4(acc[jj][4], acc[jj][5], acc[jj][6], acc[jj][7]);
            }
        }
    }
}

// sum partials + bias + relu -> mid [P][CMID]
__global__ __launch_bounds__(256) void k_reduce(const float* __restrict__ partial,
                                                const float* __restrict__ bias,
                                                float* __restrict__ mid) {
    int p = blockIdx.x, c = threadIdx.x;
    float s = bias[c];
    for (int ks = 0; ks < KS; ++ks) s += partial[(size_t)ks * P * CMID + (size_t)p * CMID + c];
    mid[(size_t)p * CMID + c] = fmaxf(s, 0.f);
}

// 1x1 heads + softmax + anchors + loc2bbox + clip. 16 positions per block (4 reps).
__global__ __launch_bounds__(256) void k_heads(const float* __restrict__ mid,
                                               const float* __restrict__ score_w,
                                               const float* __restrict__ score_b,
                                               const float* __restrict__ loc_w,
                                               const float* __restrict__ loc_b,
                                               float* __restrict__ score_out,
                                               float* __restrict__ loc_out,
                                               float* __restrict__ anch_out,
                                               float* __restrict__ fg,
                                               float* __restrict__ boxes) {
    __shared__ float wl[256][56];
    __shared__ float bias[56];
    __shared__ float dots[4][64];
    int t = threadIdx.x;
    for (int idx = t; idx < 18 * 256; idx += 256) {
        int c = idx >> 8, i = idx & 255;
        wl[i][c] = score_w[idx];
    }
    for (int idx = t; idx < 36 * 256; idx += 256) {
        int c = idx >> 8, i = idx & 255;
        wl[i][18 + c] = loc_w[idx];
    }
    if (t < 18) bias[t] = score_b[t];
    else if (t < 54) bias[t] = loc_b[t - 18];
    __syncthreads();

    int pl = t >> 6, c = t & 63;
    for (int rep = 0; rep < 4; ++rep) {
        int p = blockIdx.x * 16 + rep * 4 + pl;
        if (c < 54 && p < P) {
            float d = bias[c];
            const float4* mp = reinterpret_cast<const float4*>(mid + (size_t)p * CMID);
            for (int i4 = 0; i4 < 64; ++i4) {
                float4 m4 = mp[i4];
                int i = i4 * 4;
                d += m4.x * wl[i][c] + m4.y * wl[i + 1][c] + m4.z * wl[i + 2][c] + m4.w * wl[i + 3][c];
            }
            dots[pl][c] = d;
        }
        __syncthreads();
        if (c < NA && p < P) {
            int a = c;
            int idx = p * NA + a;
            float l0 = dots[pl][2 * a], l1 = dots[pl][2 * a + 1];
            float mx = fmaxf(l0, l1);
            float e0 = expf(l0 - mx), e1 = expf(l1 - mx);
            float den = e0 + e1;
            float s0 = e0 / den, s1 = e1 / den;
            score_out[(size_t)idx * 2 + 0] = s0;
            score_out[(size_t)idx * 2 + 1] = s1;
            fg[idx] = s1;
            float dx = dots[pl][18 + 4 * a + 0];
            float dy = dots[pl][18 + 4 * a + 1];
            float dw = dots[pl][18 + 4 * a + 2];
            float dh = dots[pl][18 + 4 * a + 3];
            loc_out[(size_t)idx * 4 + 0] = dx;
            loc_out[(size_t)idx * 4 + 1] = dy;
            loc_out[(size_t)idx * 4 + 2] = dw;
            loc_out[(size_t)idx * 4 + 3] = dh;
            int hh = p / W, ww = p % W;
            const double scales[3] = {8.0, 16.0, 32.0};
            const double ratios[3] = {0.5, 1.0, 2.0};
            double s = scales[a / 3], r = ratios[a % 3];
            double wb2 = 16.0 * s * sqrt(r);
            double hb = wb2 / r;
            double xmin = 8.0 - wb2 / 2.0, ymin = 8.0 - hb / 2.0;
            float b0 = (float)xmin, b1 = (float)ymin;
            float b2 = (float)(xmin + wb2), b3 = (float)(ymin + hb);
            float gx = (float)(ww * 16), gy = (float)(hh * 16);
            float a0 = gx + b0, a1 = gy + b1, a2 = gx + b2, a3 = gy + b3;
            anch_out[(size_t)idx * 4 + 0] = a0;
            anch_out[(size_t)idx * 4 + 1] = a1;
            anch_out[(size_t)idx * 4 + 2] = a2;
            anch_out[(size_t)idx * 4 + 3] = a3;
            float aw = a2 - a0, ah = a3 - a1;
            float cx = a0 + 0.5f * aw, cy = a1 + 0.5f * ah;
            float ncx = dx * aw + cx, ncy = dy * ah + cy;
            float nw = expf(dw) * aw, nh = expf(dh) * ah;
            float x1 = ncx - 0.5f * nw, y1 = ncy - 0.5f * nh;
            float x2 = ncx + 0.5f * nw, y2 = ncy + 0.5f * nh;
            x1 = fminf(fmaxf(x1, 0.f), (float)(W * 16));
            x2 = fminf(fmaxf(x2, 0.f), (float)(W * 16));
            y1 = fminf(fmaxf(y1, 0.f), (float)(H * 16));
            y2 = fminf(fmaxf(y2, 0.f), (float)(H * 16));
            float4* bp = reinterpret_cast<float4*>(boxes);
            bp[idx] = make_float4(x1, y1, x2, y2);
        }
        __syncthreads();
    }
}

// partial stable-descending rank counts over a j-slice. grid (67, 8)
static constexpr int JSL = 2144;  // slice size (mult of 4)
__global__ __launch_bounds__(256) void k_rank_part(const float* __restrict__ fg,
                                                   int* __restrict__ cntb) {
    __shared__ float4 tile[256];
    int t = threadIdx.x;
    int i = blockIdx.x * 256 + t;
    int j0 = blockIdx.y * JSL;
    int j1 = min(NBOX, j0 + JSL);
    float my = (i < NBOX) ? fg[i] : 0.f;
    int cnt = 0;
    for (int base = j0; base < j1; base += 1024) {
        int j = base + t * 4;
        float4 v = make_float4(-3.4e38f, -3.4e38f, -3.4e38f, -3.4e38f);
        if (j + 3 < j1) {
            v = *reinterpret_cast<const float4*>(fg + j);
        } else {
            if (j < j1) v.x = fg[j];
            if (j + 1 < j1) v.y = fg[j + 1];
            if (j + 2 < j1) v.z = fg[j + 2];
            if (j + 3 < j1) v.w = fg[j + 3];
        }
        __syncthreads();
        tile[t] = v;
        __syncthreads();
        if (i < NBOX) {
            for (int u = 0; u < 256; ++u) {
                float4 s = tile[u];
                int jb = base + u * 4;
                cnt += (s.x > my) || (s.x == my && jb < i);
                cnt += (s.y > my) || (s.y == my && jb + 1 < i);
                cnt += (s.z > my) || (s.z == my && jb + 2 < i);
                cnt += (s.w > my) || (s.w == my && jb + 3 < i);
            }
        }
    }
    if (i < NBOX && cnt) atomicAdd(&cntb[i], cnt);
}

// scatter boxes to sorted order using rank counts
__global__ __launch_bounds__(256) void k_scatter(const int* __restrict__ cntb,
                                                 const float* __restrict__ boxes,
                                                 float* __restrict__ sboxes,
                                                 float* __restrict__ sarea) {
    int i = blockIdx.x * 256 + threadIdx.x;
    if (i >= NBOX) return;
    int c = cntb[i];
    float4 b = reinterpret_cast<const float4*>(boxes)[i];
    reinterpret_cast<float4*>(sboxes)[c] = b;
    sarea[c] = (b.z - b.x) * (b.w - b.y);
}

// NMS pair bitmask, transposed: maskT[w][i] bit jb = (IoU(i, w*64+jb) > T && j > i)
__global__ __launch_bounds__(256) void k_maskfill(const float* __restrict__ sboxes,
                                                  const float* __restrict__ sarea,
                                                  U64* __restrict__ maskT) {
    int w = blockIdx.y;
    int i0 = blockIdx.x * 256;
    if (w < (i0 >> 6)) return;
    __shared__ float4 sb[64];
    __shared__ float sa[64];
    int t = threadIdx.x;
    if (t < 64) {
        int j = w * 64 + t;
        if (j < NBOX) {
            sb[t] = reinterpret_cast<const float4*>(sboxes)[j];
            sa[t] = sarea[j];
        } else {
            sb[t] = make_float4(0.f, 0.f, 0.f, 0.f);
            sa[t] = 0.f;
        }
    }
    __syncthreads();
    int i = i0 + t;
    if (i >= NBOX || w < (i >> 6)) return;
    float4 bi = reinterpret_cast<const float4*>(sboxes)[i];
    float ai = sarea[i];
    U64 word = 0;
#pragma unroll 4
    for (int jb = 0; jb < 64; ++jb) {
        int j = w * 64 + jb;
        float4 bj = sb[jb];
        float xx1 = fmaxf(bi.x, bj.x), yy1 = fmaxf(bi.y, bj.y);
        float xx2 = fminf(bi.z, bj.z), yy2 = fminf(bi.w, bj.w);
        float inter = fmaxf(xx2 - xx1, 0.f) * fmaxf(yy2 - yy1, 0.f);
        float iou = inter / (ai + sa[jb] - inter);
        word |= ((U64)((iou > NMS_T) && (j > i))) << jb;
    }
    maskT[(size_t)w * PITCH + i] = word;
}

// exact greedy sweep v3: wave-specialized, depth-2 prefetch, zero loads on the
// resolve critical path. Wave0: resolve + outputs + near-OR (register butterfly).
// Waves1-3: previous group's klist applied to far words (latency overlapped).
__global__ __launch_bounds__(256) void k_sweep(const U64* __restrict__ maskT,
                                               const float* __restrict__ sboxes,
                                               float* __restrict__ rois_out,
                                               float* __restrict__ keep_out) {
    __shared__ U64 rem[NW];
    __shared__ int klbuf[2][64];
    __shared__ int kn[2];
    __shared__ unsigned base_s;
    int t = threadIdx.x;
    for (int u = t; u < NW; u += 256) rem[u] = 0;
    if (t == 0) { base_s = 0; kn[0] = 0; kn[1] = 0; }

    // prologue prefetch: diag+near for g=0 (A regs) and g=1 (B regs)
    U64 dA = 0, nA = 0, dB = 0, nB = 0;
    if (t < 64) {
        int r0 = t;                         // group 0 rows
        dA = maskT[(size_t)0 * PITCH + r0];
        nA = maskT[(size_t)1 * PITCH + r0];
        int r1 = 64 + t;                    // group 1 rows
        dB = maskT[(size_t)1 * PITCH + r1];
        nB = maskT[(size_t)2 * PITCH + r1];
    }
    __syncthreads();

    auto body = [&](int g, U64& dR, U64& nR) {
        if (t < 64) {
            // ---- wave 0: resolve current group from registers ----
            int nv = min(64, NBOX - g * 64);
            U64 vmask = (nv == 64) ? ~0ull : ((1ull << nv) - 1);
            U64 m = rem[g];
            U64 notsup = ~m & vmask;
            U64 kept = 0;
            while (notsup) {
                int i = (int)__builtin_ctzll(notsup);
                kept |= (1ull << i);
                U64 wi = rdlane64(dR, i);
                notsup &= ~(wi | (1ull << i));
            }
            int nk = __popcll(kept);
            bool mine = (kept >> t) & 1ull;

            // near-OR: contribution of this group's kept rows to rem[g+1],
            // entirely from prefetched registers (butterfly reduce)
            U64 val = mine ? nR : 0;
#pragma unroll
            for (int s = 1; s < 64; s <<= 1) val |= (U64)__shfl_xor((unsigned long long)val, s, 64);
            if (t == 0 && g + 1 < NW && val) atomicOr(&rem[g + 1], val);

            // refill prefetch registers for group g+2 (consumed 2 rounds later)
            if (g + 2 < NW) {
                int row = (g + 2) * 64 + t;
                dR = (row < NBOX) ? maskT[(size_t)(g + 2) * PITCH + row] : 0;
                nR = (row < NBOX && g + 3 < NW) ? maskT[(size_t)(g + 3) * PITCH + row] : 0;
            }

            // outputs + klist publish
            unsigned base = base_s;
            if (mine) {
                unsigned pre = (unsigned)__popcll(kept & ((1ull << t) - 1));
                unsigned dst = base + pre;
                float4 bb = reinterpret_cast<const float4*>(sboxes)[g * 64 + t];
                reinterpret_cast<float4*>(rois_out)[dst] = bb;
                keep_out[dst] = 1.0f;
                klbuf[g & 1][pre] = t;
            }
            if (t == 0) {
                kn[g & 1] = nk;
                base_s = base + (unsigned)nk;
            }
        } else if (g >= 1) {
            // ---- waves 1-3: apply klist[g-1] to far words w in [g+1, NW) ----
            int pb = (g - 1) & 1;
            int nkp = kn[pb];
            if (nkp) {
                const size_t colbase = (size_t)(g - 1) * 64;
                for (int w = g + 1 + (t - 64); w < NW; w += 192) {
                    const U64* col = maskT + (size_t)w * PITCH + colbase;
                    U64 acc = 0;
                    int b = 0;
                    for (; b + 3 < nkp; b += 4) {
                        U64 v0 = col[klbuf[pb][b]];
                        U64 v1 = col[klbuf[pb][b + 1]];
                        U64 v2 = col[klbuf[pb][b + 2]];
                        U64 v3 = col[klbuf[pb][b + 3]];
                        acc |= v0 | v1 | v2 | v3;
                    }
                    for (; b < nkp; ++b) acc |= col[klbuf[pb][b]];
                    if (acc) atomicOr(&rem[w], acc);
                }
            }
        }
        __syncthreads();
    };

    for (int gg = 0; gg < NW; gg += 2) {
        body(gg, dA, nA);
        body(gg + 1, dB, nB);
    }
}

// ---------------- launch ----------------
extern "C" void kernel_launch(void* const* d_in, const int* in_sizes, int n_in,
                              void* d_out, int out_size, void* d_ws, size_t ws_size,
                              hipStream_t stream) {
    const float* fm      = (const float*)d_in[0];
    const float* conv_w  = (const float*)d_in[2];
    const float* conv_b  = (const float*)d_in[3];
    const float* score_w = (const float*)d_in[4];
    const float* score_b = (const float*)d_in[5];
    const float* loc_w   = (const float*)d_in[6];
    const float* loc_b   = (const float*)d_in[7];

    float* out = (float*)d_out;
    float* rois_out  = out;
    float* keep_out  = out + NBOX * 4;
    float* anch_out  = out + NBOX * 5;
    float* loc_out   = out + NBOX * 9;
    float* score_out = out + NBOX * 13;

    if (ws_size < WS_NEED) {
        k_sentinel<<<(out_size + 255) / 256, 256, 0, stream>>>(out, out_size);
        return;
    }

    char* ws = (char*)d_ws;
    float* in_tT   = (float*)(ws + OFF_INT);
    float* w2      = (float*)(ws + OFF_WT);
    float* partial = (float*)(ws + OFF_PART);
    U64*   maskT   = (U64*)(ws + OFF_MASK);
    float* mid     = (float*)(ws + OFF_MID);
    float* fg      = (float*)(ws + OFF_FG);
    float* boxes   = (float*)(ws + OFF_BOX);
    float* sboxes  = (float*)(ws + OFF_SBOX);
    float* sarea   = (float*)(ws + OFF_SAREA);
    int*   cntb    = (int*)(ws + OFF_CNT);

    hipMemsetAsync(in_tT, 0, SZ_INT, stream);
    k_in_t<<<(CIN * H * W + 255) / 256, 256, 0, stream>>>(fm, in_tT);
    k_w_t<<<(CMID * CIN * 9 + 255) / 256, 256, 0, stream>>>(conv_w, w2);
    k_conv<<<504, 256, 0, stream>>>(in_tT, w2, partial);
    k_reduce<<<P, 256, 0, stream>>>(partial, conv_b, mid);
    k_heads<<<(P + 15) / 16, 256, 0, stream>>>(mid, score_w, score_b, loc_w, loc_b,
                                               score_out, loc_out, anch_out, fg, boxes);
    hipMemsetAsync(cntb, 0, NBOX * 4, stream);
    k_rank_part<<<dim3((NBOX + 255) / 256, 8), 256, 0, stream>>>(fg, cntb);
    k_scatter<<<(NBOX + 255) / 256, 256, 0, stream>>>(cntb, boxes, sboxes, sarea);
    hipMemsetAsync(rois_out, 0, (size_t)NBOX * 5 * 4, stream);  // rois_out + keep
    k_maskfill<<<dim3((NBOX + 255) / 256, NW), 256, 0, stream>>>(sboxes, sarea, maskT);
    k_sweep<<<1, 256, 0, stream>>>(maskT, sboxes, rois_out, keep_out);
}